// Round 11
// baseline (659.003 us; speedup 1.0000x reference)
//
#include <hip/hip_runtime.h>
#include <math.h>

#define HW 12544      // 112*112
#define W_IMG 112
#define B_SZ 2

typedef __attribute__((ext_vector_type(8))) short s8v;   // 8 bf16 (4 VGPRs)
typedef __attribute__((ext_vector_type(4))) float f4v;   // MFMA acc

__device__ __forceinline__ void split_bf16(float x, unsigned short& h, unsigned short& l) {
    unsigned u  = __float_as_uint(x);
    unsigned hb = (u + 0x7FFFu + ((u >> 16) & 1u)) >> 16;
    float hf    = __uint_as_float(hb << 16);
    float r     = x - hf;
    unsigned ur = __float_as_uint(r);
    unsigned lb = (ur + 0x7FFFu + ((ur >> 16) & 1u)) >> 16;
    h = (unsigned short)hb; l = (unsigned short)lb;
}

// ---------------------------------------------------------------------------
// Weight split -> blocked transposed-quad bf16 hi/lo:
// [mblk(64 rows)][kc][kq(4)][64 rows][8 shorts].
// Rows [0,O1) from src, rows [o2base, o2base+O2) from src2 (scaled), else 0.
// ---------------------------------------------------------------------------
struct WSplitArgs {
    const float* src[8];
    const float* src2[8];
    unsigned short* hi[8];
    unsigned short* lo[8];
    int O1[8]; int O2[8]; int O2B[8]; int K[8]; int Kp[8]; int MpKp[8];
    float scale2[8];
};

__global__ __launch_bounds__(256) void wsplit_k(WSplitArgs a) {
    const int ci  = blockIdx.y;
    const int idx = blockIdx.x * 256 + threadIdx.x;
    if (idx >= a.MpKp[ci]) return;
    const int Kp   = a.Kp[ci];
    const int blk  = 64 * Kp;              // shorts per m-block = KC*2048
    const int mblk = idx / blk;
    const int rem  = idx - mblk * blk;
    const int kc   = rem >> 11;            // /2048
    const int rem2 = rem & 2047;
    const int kq   = rem2 >> 9;            // /512
    const int row  = (rem2 >> 3) & 63;
    const int j    = rem2 & 7;
    const int o = mblk * 64 + row, k = kc * 32 + kq * 8 + j;
    float v = 0.f;
    if (k < a.K[ci]) {
        if (o < a.O1[ci])
            v = a.src[ci][(size_t)o * a.K[ci] + k];
        else if (o >= a.O2B[ci] && o - a.O2B[ci] < a.O2[ci])
            v = a.src2[ci][(size_t)(o - a.O2B[ci]) * a.K[ci] + k] * a.scale2[ci];
    }
    unsigned short h, l;
    split_bf16(v, h, l);
    a.hi[ci][idx] = h; a.lo[ci][idx] = l;
}

// ---------------------------------------------------------------------------
// Transpose + split: fp32 [C][HW] -> blocked transposed-quad bf16 hi/lo
// [b][strip(49)][kc][kq(4)][256 rows][8 shorts].  grid (392, KC, B), block 256.
// ---------------------------------------------------------------------------
__global__ __launch_bounds__(256) void tsplit_k(
    const float* __restrict__ src, size_t bstride, int C, int KC,
    unsigned short* __restrict__ hi, unsigned short* __restrict__ lo)
{
    __shared__ __align__(16) float t[32][36];
    const int b   = blockIdx.z;
    const int hw0 = blockIdx.x * 32;
    const int kc  = blockIdx.y;
    const int c0  = kc * 32;
    const int tid = threadIdx.x;

    {
        const int cl = tid >> 3, hq = (tid & 7) * 4;
        const int c  = c0 + cl;
        float4 v = make_float4(0.f, 0.f, 0.f, 0.f);
        if (c < C)
            v = *(const float4*)(src + (size_t)b * bstride + (size_t)c * HW + hw0 + hq);
        *(float4*)&t[cl][hq] = v;
    }
    __syncthreads();

    const int hl = tid >> 3, cq = (tid & 7) * 4;
    float v0 = t[cq + 0][hl], v1 = t[cq + 1][hl], v2 = t[cq + 2][hl], v3 = t[cq + 3][hl];
    ushort4 h4, l4;
    split_bf16(v0, h4.x, l4.x);
    split_bf16(v1, h4.y, l4.y);
    split_bf16(v2, h4.z, l4.z);
    split_bf16(v3, h4.w, l4.w);
    const int ns = hw0 >> 8, r = (hw0 & 255) + hl;
    const int kq = cq >> 3, j0 = cq & 7;
    const size_t base = (((size_t)b * 49 + ns) * KC + kc) * 8192
                        + (size_t)kq * 2048 + (size_t)r * 8 + j0;
    *(ushort4*)(hi + base) = h4;
    *(ushort4*)(lo + base) = l4;
}

// ---------------------------------------------------------------------------
// Split-bf16 MFMA GEMM, LDS-staged, transposed-quad layout (conflict-free).
// Block tile: M=64 (4 m-tiles) x N=256; 4 waves, wave = M64 x N64.
// Per 32-k chunk: contiguous-memcpy stage of B (32KB) + A (8KB) into LDS,
// then ds_read_b128 fragments (<=2-way bank aliasing) + 48 MFMAs/wave.
// XCD swizzle keeps all m-blocks of an n-strip on one XCD (B L2-resident).
// fp32 out: o<OA -> outA; o in [obase,obase+OB) -> outB[o-obase].
// mode 2: tanh+res, 3: (tanh+res)*mul — applied only for o<Ovalid.
// grid (per_m*56, B), block 256.
// ---------------------------------------------------------------------------
template <int KP>
__global__ __launch_bounds__(256) void gemm_k(
    const unsigned short* __restrict__ bt_hi, const unsigned short* __restrict__ bt_lo,
    const unsigned short* __restrict__ w_hi,  const unsigned short* __restrict__ w_lo,
    int per_m,
    float* __restrict__ outA, int OA, size_t oa_bstride,
    float* __restrict__ outB, int OB, size_t ob_bstride, int obase,
    int mode, int Ovalid,
    const float* __restrict__ res, size_t res_bstride,
    const float* __restrict__ mul, size_t mul_bstride)
{
    constexpr int KC = KP / 32;
    __shared__ __align__(16) unsigned short Bh_s[8192];   // [kq][256][8]
    __shared__ __align__(16) unsigned short Bl_s[8192];
    __shared__ __align__(16) unsigned short Ah_s[2048];   // [kq][64][8]
    __shared__ __align__(16) unsigned short Al_s[2048];

    const int b   = blockIdx.y;
    const int bx  = blockIdx.x;
    const int xcd = bx & 7, t = bx >> 3;
    const int m   = t % per_m;
    const int ns  = (t / per_m) * 8 + xcd;
    if (ns >= 49) return;

    const int tid  = threadIdx.x;
    const int wv   = tid >> 6, lane = tid & 63;
    const int m16  = lane & 15, quad = lane >> 4;
    const int mbase = m * 64;
    const int nbase = ns * 256 + wv * 64;

    const unsigned short* Bh_g = bt_hi + ((size_t)b * 49 + ns) * KC * 8192;
    const unsigned short* Bl_g = bt_lo + ((size_t)b * 49 + ns) * KC * 8192;
    const unsigned short* Ah_g = w_hi + (size_t)m * KC * 2048;
    const unsigned short* Al_g = w_lo + (size_t)m * KC * 2048;

    f4v acc[4][4];
#pragma unroll
    for (int mt = 0; mt < 4; ++mt)
#pragma unroll
        for (int f = 0; f < 4; ++f) acc[mt][f] = (f4v){0.f, 0.f, 0.f, 0.f};

#pragma unroll
    for (int kc = 0; kc < KC; ++kc) {
        // ---- stage chunk kc (contiguous memcpy image; coalesced & conflict-free)
        {
            const unsigned short* bh = Bh_g + (size_t)kc * 8192;
            const unsigned short* bl = Bl_g + (size_t)kc * 8192;
            s8v vb0 = *(const s8v*)(bh + (size_t)tid * 8);
            s8v vb1 = *(const s8v*)(bh + (size_t)(256 + tid) * 8);
            s8v vb2 = *(const s8v*)(bh + (size_t)(512 + tid) * 8);
            s8v vb3 = *(const s8v*)(bh + (size_t)(768 + tid) * 8);
            s8v wb0 = *(const s8v*)(bl + (size_t)tid * 8);
            s8v wb1 = *(const s8v*)(bl + (size_t)(256 + tid) * 8);
            s8v wb2 = *(const s8v*)(bl + (size_t)(512 + tid) * 8);
            s8v wb3 = *(const s8v*)(bl + (size_t)(768 + tid) * 8);
            s8v va  = *(const s8v*)(Ah_g + (size_t)kc * 2048 + (size_t)tid * 8);
            s8v wa  = *(const s8v*)(Al_g + (size_t)kc * 2048 + (size_t)tid * 8);
            *(s8v*)(Bh_s + tid * 8)         = vb0;
            *(s8v*)(Bh_s + (256 + tid) * 8) = vb1;
            *(s8v*)(Bh_s + (512 + tid) * 8) = vb2;
            *(s8v*)(Bh_s + (768 + tid) * 8) = vb3;
            *(s8v*)(Bl_s + tid * 8)         = wb0;
            *(s8v*)(Bl_s + (256 + tid) * 8) = wb1;
            *(s8v*)(Bl_s + (512 + tid) * 8) = wb2;
            *(s8v*)(Bl_s + (768 + tid) * 8) = wb3;
            *(s8v*)(Ah_s + tid * 8)         = va;
            *(s8v*)(Al_s + tid * 8)         = wa;
        }
        __syncthreads();

        // ---- compute: fragments from LDS (lane addr = quad*plane + row*16B)
#pragma unroll
        for (int mt = 0; mt < 4; ++mt) {
            s8v ah = *(const s8v*)(Ah_s + (quad * 64 + mt * 16 + m16) * 8);
            s8v al = *(const s8v*)(Al_s + (quad * 64 + mt * 16 + m16) * 8);
#pragma unroll
            for (int f = 0; f < 4; ++f) {
                const int row = wv * 64 + f * 16 + m16;
                s8v bh = *(const s8v*)(Bh_s + (quad * 256 + row) * 8);
                s8v bl = *(const s8v*)(Bl_s + (quad * 256 + row) * 8);
                acc[mt][f] = __builtin_amdgcn_mfma_f32_16x16x32_bf16(ah, bh, acc[mt][f], 0, 0, 0);
                acc[mt][f] = __builtin_amdgcn_mfma_f32_16x16x32_bf16(al, bh, acc[mt][f], 0, 0, 0);
                acc[mt][f] = __builtin_amdgcn_mfma_f32_16x16x32_bf16(ah, bl, acc[mt][f], 0, 0, 0);
            }
        }
        if (kc + 1 < KC) __syncthreads();
    }

    // ---- epilogue ----
#pragma unroll
    for (int mt = 0; mt < 4; ++mt) {
#pragma unroll
        for (int f = 0; f < 4; ++f) {
            const int n = nbase + f * 16 + m16;
#pragma unroll
            for (int r = 0; r < 4; ++r) {
                const int o = mbase + mt * 16 + quad * 4 + r;
                float v = acc[mt][f][r];
                if (mode == 2) {
                    if (o < Ovalid)
                        v = tanhf(v) + res[(size_t)b * res_bstride + (size_t)o * HW + n];
                } else if (mode == 3) {
                    if (o < Ovalid)
                        v = (tanhf(v) + res[(size_t)b * res_bstride + (size_t)o * HW + n])
                            * mul[(size_t)b * mul_bstride + (size_t)o * HW + n];
                }
                if (o < OA) {
                    outA[(size_t)b * oa_bstride + (size_t)o * HW + n] = v;
                } else if (o >= obase && o - obase < OB) {
                    outB[(size_t)b * ob_bstride + (size_t)(o - obase) * HW + n] = v;
                }
            }
        }
    }
}

// ---------------------------------------------------------------------------
// 16x16 block mean-pool 112x112 -> 7x7.  grid (C, B), block 64 (49 active).
// ---------------------------------------------------------------------------
__global__ __launch_bounds__(64) void pool_k(
    const float* __restrict__ ctx, float* __restrict__ pooled, int C)
{
    const int c = blockIdx.x, b = blockIdx.y, t = threadIdx.x;
    if (t >= 49) return;
    const int ph = t / 7, pw = t % 7;
    const float* src = ctx + ((size_t)b * C + c) * HW;
    float sum = 0.f;
    for (int i = 0; i < 16; ++i) {
        const float* row = src + (ph * 16 + i) * W_IMG + pw * 16;
        for (int j = 0; j < 16; ++j) sum += row[j];
    }
    pooled[((size_t)b * C + c) * 49 + t] = sum * (1.0f / 256.0f);
}

// ---------------------------------------------------------------------------
// key[b,o,l] = sum_c wk[o,c] * pooled[b,c,l].  grid (O, B), block 64.
// ---------------------------------------------------------------------------
__global__ __launch_bounds__(64) void keygemm_k(
    const float* __restrict__ pooled, const float* __restrict__ wk,
    float* __restrict__ key, int K, int O)
{
    const int o = blockIdx.x, b = blockIdx.y, l = threadIdx.x;
    if (l >= 49) return;
    float s = 0.f;
    for (int c = 0; c < K; ++c)
        s += wk[(size_t)o * K + c] * pooled[((size_t)b * K + c) * 49 + l];
    key[((size_t)b * O + o) * 49 + l] = s;
}

// ---------------------------------------------------------------------------
// Attention scores + double softmax.  attn layout [b][g][18][HW] (tap-major).
// grid (49, 2, B), block 256.
// ---------------------------------------------------------------------------
__global__ __launch_bounds__(256) void attn_k(
    const float* __restrict__ q, const float* __restrict__ key,
    const float* __restrict__ wp, const float* __restrict__ pb,
    float* __restrict__ attn, int hd)
{
    __shared__ float klds[86 * 52];
    __shared__ float plds[18 * 52];
    __shared__ float pblds[18];

    const int b = blockIdx.z, g = blockIdx.y, tid = threadIdx.x;

    for (int idx = tid; idx < hd * 49; idx += 256) {
        int c = idx / 49, l = idx - c * 49;
        klds[c * 52 + l] = key[((size_t)(b * 2 + g) * hd + c) * 49 + l];
    }
    for (int idx = tid; idx < hd * 3; idx += 256) {
        int c = idx / 3;
        klds[c * 52 + 49 + (idx - c * 3)] = 0.f;
    }
    for (int idx = tid; idx < 18 * 49; idx += 256) {
        int o = idx / 49, l = idx - o * 49;
        plds[o * 52 + l] = wp[o * 49 + l];
    }
    for (int idx = tid; idx < 18 * 3; idx += 256) {
        int o = idx / 3;
        plds[o * 52 + 49 + (idx - o * 3)] = 0.f;
    }
    if (tid < 18) pblds[tid] = pb[tid];
    __syncthreads();

    const int hw = blockIdx.x * 256 + tid;

    float4 s[13];
#pragma unroll
    for (int t = 0; t < 13; ++t) s[t] = make_float4(0.f, 0.f, 0.f, 0.f);

    const float* qp = q + (size_t)(b * 2 + g) * hd * HW + hw;
    for (int c = 0; c < hd; ++c) {
        float qv = qp[(size_t)c * HW];
        const float4* kr = (const float4*)(klds + c * 52);
#pragma unroll
        for (int t = 0; t < 13; ++t) {
            float4 kv = kr[t];
            s[t].x += qv * kv.x; s[t].y += qv * kv.y;
            s[t].z += qv * kv.z; s[t].w += qv * kv.w;
        }
    }

    float e[18];
#pragma unroll
    for (int o = 0; o < 18; ++o) {
        const float4* pr = (const float4*)(plds + o * 52);
        float4 a = make_float4(0.f, 0.f, 0.f, 0.f);
#pragma unroll
        for (int t = 0; t < 13; ++t) {
            float4 pv = pr[t];
            a.x += s[t].x * pv.x; a.y += s[t].y * pv.y;
            a.z += s[t].z * pv.z; a.w += s[t].w * pv.w;
        }
        e[o] = pblds[o] + a.x + a.y + a.z + a.w;
    }

    float* outp = attn + (size_t)(b * 2 + g) * 18 * HW + hw;
#pragma unroll
    for (int half = 0; half < 2; ++half) {
        int base = half * 9;
        float m = e[base];
#pragma unroll
        for (int k = 1; k < 9; ++k) m = fmaxf(m, e[base + k]);
        float sum = 0.f, ex[9];
#pragma unroll
        for (int k = 0; k < 9; ++k) { ex[k] = expf(e[base + k] - m); sum += ex[k]; }
        float inv = 1.0f / sum;
#pragma unroll
        for (int k = 0; k < 9; ++k) outp[(size_t)(base + k) * HW] = ex[k] * inv;
    }
}

// ---------------------------------------------------------------------------
// Dynamic depthwise 3x3 mix, tap-major attn layout. grid (49, C, B), block 256.
// ---------------------------------------------------------------------------
__global__ __launch_bounds__(256) void dyndw_k(
    const float* __restrict__ x, const float* __restrict__ attn,
    float* __restrict__ y, int C, int C_half, int hd, size_t x_bstride)
{
    const int b = blockIdx.z, c = blockIdx.y;
    const int hw = blockIdx.x * 256 + threadIdx.x;
    const int h = hw / W_IMG, w = hw - h * W_IMG;

    const int half = c / C_half;
    const int g = (c - half * C_half) / hd;

    const float* ap = attn + ((size_t)(b * 2 + g) * 18 + half * 9) * HW + hw;
    float a[9];
#pragma unroll
    for (int k = 0; k < 9; ++k) a[k] = ap[(size_t)k * HW];

    const float* xp = x + (size_t)b * x_bstride + (size_t)c * HW;
    float s = 0.f;
#pragma unroll
    for (int i = 0; i < 3; ++i) {
        int hh = h + i - 1;
#pragma unroll
        for (int j = 0; j < 3; ++j) {
            int ww = w + j - 1;
            float v = (hh >= 0 && hh < 112 && ww >= 0 && ww < 112)
                          ? xp[hh * W_IMG + ww] : 0.f;
            s += v * a[i * 3 + j];
        }
    }
    y[((size_t)b * C + c) * HW + hw] = s;
}

// ---------------------------------------------------------------------------
extern "C" void kernel_launch(void* const* d_in, const int* in_sizes, int n_in,
                              void* d_out, int out_size, void* d_ws, size_t ws_size,
                              hipStream_t stream) {
    const float* x      = (const float*)d_in[0];
    const float* pin_w  = (const float*)d_in[1];
    const float* ctx_w  = (const float*)d_in[2];
    const float* ctx1_w = (const float*)d_in[3];
    const float* ctx2_w = (const float*)d_in[4];
    const float* pout_w = (const float*)d_in[5];
    const float* cm0_q  = (const float*)d_in[6];
    const float* cm0_k  = (const float*)d_in[7];
    const float* cm0_p  = (const float*)d_in[8];
    const float* cm0_pb = (const float*)d_in[9];
    const float* cm0_o  = (const float*)d_in[10];
    const float* cm1_q  = (const float*)d_in[11];
    const float* cm1_k  = (const float*)d_in[12];
    const float* cm1_p  = (const float*)d_in[13];
    const float* cm1_pb = (const float*)d_in[14];
    const float* cm1_o  = (const float*)d_in[15];
    const float* cm2_q  = (const float*)d_in[16];
    const float* cm2_k  = (const float*)d_in[17];
    const float* cm2_p  = (const float*)d_in[18];
    const float* cm2_pb = (const float*)d_in[19];
    const float* cm2_o  = (const float*)d_in[20];
    float* out = (float*)d_out;

    float* ws = (float*)d_ws;
    // ---- fp32 region (floats, ends 35449568 = 141.8 MB) ----
    float* x_in  = ws;                          // [2,344,HW]
    float* x1p   = ws;                          // [2,172,HW] (after x_in dead)
    float* y0    = ws + 8630272;                // [2,344,HW]
    float* y1    = ws + 8630272;                // [2,172,HW]
    float* prod  = ws + 8630272;                // [2,172,HW] (after y1 dead)
    float* y2    = ws + 12945408;               // [2,172,HW]
    float* x_dw  = ws + 17260544;               // [2,344,HW]
    float* ctxb  = ws + 25890816;               // [2,86,HW]
    float* ctx1  = ws + 28048384;               // [2,43,HW]
    float* ctx2  = ws + 29127168;               // [2,43,HW]
    float* q0    = ws + 30205952;               // [2,172,HW]
    float* q1    = ws + 30205952;               // [2,86,HW]
    float* q2    = ws + 32363520;               // [2,86,HW]
    float* attnb = ws + 34521088;               // [2,2,18,HW]
    float* pooled= ws + 35424256;               // [2,86,49]
    float* keyb  = ws + 35432704;               // [2,172,49]
    // ---- bf16 region (ushorts; ends 41005056 sh = 82.0 MB; total ws 223.8 MB) ----
    unsigned short* ub = (unsigned short*)(ws + 35449568);
    // conv entries: 0 pin | 1 ctx+q0 | 2 cm0_o(restacked 172/192) | 3 ctx1+q1
    //               4 ctx2+q2 | 5 cm1_o | 6 cm2_o | 7 pout   (Mp mult of 64)
    static const int WOFF[8] = {0, 49152, 274432, 544768, 618496, 692224, 765952, 839680};
    static const int WO1[8]  = {344, 86, 172, 43, 43, 172, 172, 64};
    static const int WO2[8]  = {0, 172, 172, 86, 86, 0, 0, 0};
    static const int O2B[8]  = {352, 86, 192, 43, 43, 192, 192, 64};
    static const int WK[8]   = {64, 344, 344, 172, 172, 172, 172, 172};
    static const int WKP[8]  = {64, 352, 352, 192, 192, 192, 192, 192};
    static const int WMP[8]  = {384, 320, 384, 192, 192, 192, 192, 64};
    // X_t planes (weights end at 864256)
    unsigned short* xt_hi   = ub + 864256;      // [2][49][2][8192]
    unsigned short* xt_lo   = ub + 2469888;     // end 4075520
    // bigA slab [2][49][11][8192]; serially reused: xint -> yt -> pt(KC=6)
    unsigned short* bigA_hi = ub + 4075520;
    unsigned short* bigA_lo = ub + 12906496;    // end 21737472
    unsigned short* x1t_hi  = ub + 21737472;    // [2][49][6][8192]; later y1t
    unsigned short* x1t_lo  = ub + 26554368;    // end 31371264
    unsigned short* x2t_hi  = ub + 31371264;    // later y2t
    unsigned short* x2t_lo  = ub + 36188160;    // end 41005056

    const float sc0 = 1.0f / sqrtf(86.0f);
    const float sc1 = 1.0f / sqrtf(43.0f);
    const size_t BS344 = (size_t)344 * HW, BS172 = (size_t)172 * HW,
                 BS86 = (size_t)86 * HW, BS64 = (size_t)64 * HW, BS43 = (size_t)43 * HW;

    // ---- 0. split/restack all weights (q-scales folded in, blocked layout) ----
    WSplitArgs wa;
    const float* wsrc1[8] = {pin_w, ctx_w, cm0_o, ctx1_w, ctx2_w, cm1_o, cm2_o, pout_w};
    const float* wsrc2[8] = {nullptr, cm0_q, cm0_o + (size_t)172 * 344, cm1_q, cm2_q,
                             nullptr, nullptr, nullptr};
    const float wsc2[8]   = {1.f, sc0, 1.f, sc1, sc1, 1.f, 1.f, 1.f};
    for (int i = 0; i < 8; ++i) {
        wa.src[i] = wsrc1[i]; wa.src2[i] = wsrc2[i];
        wa.hi[i]  = ub + WOFF[i];
        wa.lo[i]  = ub + WOFF[i] + WMP[i] * WKP[i];
        wa.O1[i] = WO1[i]; wa.O2[i] = WO2[i]; wa.O2B[i] = O2B[i];
        wa.K[i] = WK[i]; wa.Kp[i] = WKP[i];
        wa.MpKp[i] = WMP[i] * WKP[i];
        wa.scale2[i] = wsc2[i];
    }
    wsplit_k<<<dim3(528, 8), 256, 0, stream>>>(wa);

#define WHI(CI) (ub + WOFF[CI])
#define WLO(CI) (ub + WOFF[CI] + WMP[CI] * WKP[CI])
#define GRID(CI) dim3((WMP[CI] / 64) * 56, B_SZ)

    // ---- pin: x_in = pin_w @ x ----
    tsplit_k<<<dim3(392, 2, B_SZ), 256, 0, stream>>>(x, BS64, 64, 2, xt_hi, xt_lo);
    gemm_k<64><<<GRID(0), 256, 0, stream>>>(
        xt_hi, xt_lo, WHI(0), WLO(0), WMP[0] / 64,
        x_in, 344, BS344, nullptr, 0, 0, 384, 0, 344,
        nullptr, 0, nullptr, 0);
    tsplit_k<<<dim3(392, 11, B_SZ), 256, 0, stream>>>(x_in, BS344, 344, 11, bigA_hi, bigA_lo);

    // ---- contmix0: fused ctx_dw + q0 ----
    gemm_k<352><<<GRID(1), 256, 0, stream>>>(
        bigA_hi, bigA_lo, WHI(1), WLO(1), WMP[1] / 64,
        ctxb, 86, BS86, q0, 172, BS172, 86, 0, 258,
        nullptr, 0, nullptr, 0);
    pool_k<<<dim3(86, B_SZ), dim3(64), 0, stream>>>(ctxb, pooled, 86);
    keygemm_k<<<dim3(172, B_SZ), dim3(64), 0, stream>>>(pooled, cm0_k, keyb, 86, 172);
    attn_k<<<dim3(49, 2, B_SZ), dim3(256), 0, stream>>>(q0, keyb, cm0_p, cm0_pb, attnb, 86);
    dyndw_k<<<dim3(49, 344, B_SZ), dim3(256), 0, stream>>>(x_in, attnb, y0, 344, 172, 86, BS344);
    tsplit_k<<<dim3(392, 11, B_SZ), 256, 0, stream>>>(y0, BS344, 344, 11, bigA_hi, bigA_lo);
    // x_dw = cm0_o @ y  (restacked: rows 0..172 -> x1, 192..364 -> x2)
    gemm_k<352><<<GRID(2), 256, 0, stream>>>(
        bigA_hi, bigA_lo, WHI(2), WLO(2), WMP[2] / 64,
        x_dw, 172, BS344, x_dw + BS172, 172, BS344, 192, 0, 384,
        nullptr, 0, nullptr, 0);

    // ---- transpose halves of x_dw ----
    tsplit_k<<<dim3(392, 6, B_SZ), 256, 0, stream>>>(x_dw, BS344, 172, 6, x1t_hi, x1t_lo);
    tsplit_k<<<dim3(392, 6, B_SZ), 256, 0, stream>>>(x_dw + BS172, BS344, 172, 6, x2t_hi, x2t_lo);

    // ---- contmix1 on x1 ----
    gemm_k<192><<<GRID(3), 256, 0, stream>>>(
        x1t_hi, x1t_lo, WHI(3), WLO(3), WMP[3] / 64,
        ctx1, 43, BS43, q1, 86, BS86, 43, 0, 129,
        nullptr, 0, nullptr, 0);
    pool_k<<<dim3(43, B_SZ), dim3(64), 0, stream>>>(ctx1, pooled, 43);
    keygemm_k<<<dim3(86, B_SZ), dim3(64), 0, stream>>>(pooled, cm1_k, keyb, 43, 86);
    attn_k<<<dim3(49, 2, B_SZ), dim3(256), 0, stream>>>(q1, keyb, cm1_p, cm1_pb, attnb, 43);
    dyndw_k<<<dim3(49, 172, B_SZ), dim3(256), 0, stream>>>(x_dw, attnb, y1, 172, 86, 43, BS344);
    tsplit_k<<<dim3(392, 6, B_SZ), 256, 0, stream>>>(y1, BS172, 172, 6, x1t_hi, x1t_lo);
    // x1p = tanh(cm1_o @ y1) + x1
    gemm_k<192><<<GRID(5), 256, 0, stream>>>(
        x1t_hi, x1t_lo, WHI(5), WLO(5), WMP[5] / 64,
        x1p, 172, BS172, nullptr, 0, 0, 192, 2, 172,
        x_dw, BS344, nullptr, 0);

    // ---- contmix2 on x2 ----
    gemm_k<192><<<GRID(4), 256, 0, stream>>>(
        x2t_hi, x2t_lo, WHI(4), WLO(4), WMP[4] / 64,
        ctx2, 43, BS43, q2, 86, BS86, 43, 0, 129,
        nullptr, 0, nullptr, 0);
    pool_k<<<dim3(43, B_SZ), dim3(64), 0, stream>>>(ctx2, pooled, 43);
    keygemm_k<<<dim3(86, B_SZ), dim3(64), 0, stream>>>(pooled, cm2_k, keyb, 43, 86);
    attn_k<<<dim3(49, 2, B_SZ), dim3(256), 0, stream>>>(q2, keyb, cm2_p, cm2_pb, attnb, 43);
    dyndw_k<<<dim3(49, 172, B_SZ), dim3(256), 0, stream>>>(x_dw + BS172, attnb, y2, 172, 86, 43, BS344);
    tsplit_k<<<dim3(392, 6, B_SZ), 256, 0, stream>>>(y2, BS172, 172, 6, x2t_hi, x2t_lo);
    // prod = (tanh(cm2_o @ y2) + x2) * x1p
    gemm_k<192><<<GRID(6), 256, 0, stream>>>(
        x2t_hi, x2t_lo, WHI(6), WLO(6), WMP[6] / 64,
        prod, 172, BS172, nullptr, 0, 0, 192, 3, 172,
        x_dw + BS172, BS344, x1p, BS172);

    // ---- pout ----
    tsplit_k<<<dim3(392, 6, B_SZ), 256, 0, stream>>>(prod, BS172, 172, 6, bigA_hi, bigA_lo);
    gemm_k<192><<<GRID(7), 256, 0, stream>>>(
        bigA_hi, bigA_lo, WHI(7), WLO(7), WMP[7] / 64,
        out, 64, BS64, nullptr, 0, 0, 64, 0, 64,
        nullptr, 0, nullptr, 0);

#undef WHI
#undef WLO
#undef GRID
}

// Round 12
// 555.142 us; speedup vs baseline: 1.1871x; 1.1871x over previous
//
#include <hip/hip_runtime.h>
#include <math.h>

#define HW 12544      // 112*112
#define W_IMG 112
#define B_SZ 2

typedef __attribute__((ext_vector_type(8))) short s8v;   // 8 bf16 (4 VGPRs)
typedef __attribute__((ext_vector_type(4))) float f4v;   // MFMA acc

__device__ __forceinline__ void split_bf16(float x, unsigned short& h, unsigned short& l) {
    unsigned u  = __float_as_uint(x);
    unsigned hb = (u + 0x7FFFu + ((u >> 16) & 1u)) >> 16;
    float hf    = __uint_as_float(hb << 16);
    float r     = x - hf;
    unsigned ur = __float_as_uint(r);
    unsigned lb = (ur + 0x7FFFu + ((ur >> 16) & 1u)) >> 16;
    h = (unsigned short)hb; l = (unsigned short)lb;
}

// ---------------------------------------------------------------------------
// Weight split -> blocked transposed-quad bf16 hi/lo:
// [mblk(32 rows)][kc][kq(4)][32 rows][8 shorts].
// Rows [0,O1) from src, rows [o2base, o2base+O2) from src2 (scaled), else 0.
// ---------------------------------------------------------------------------
struct WSplitArgs {
    const float* src[8];
    const float* src2[8];
    unsigned short* hi[8];
    unsigned short* lo[8];
    int O1[8]; int O2[8]; int O2B[8]; int K[8]; int Kp[8]; int MpKp[8];
    float scale2[8];
};

__global__ __launch_bounds__(256) void wsplit_k(WSplitArgs a) {
    const int ci  = blockIdx.y;
    const int idx = blockIdx.x * 256 + threadIdx.x;
    if (idx >= a.MpKp[ci]) return;
    const int Kp   = a.Kp[ci];
    const int blk  = 32 * Kp;              // shorts per m-block = KC*1024
    const int mblk = idx / blk;
    const int rem  = idx - mblk * blk;
    const int kc   = rem >> 10;            // /1024
    const int rem2 = rem & 1023;
    const int kq   = rem2 >> 8;            // /256
    const int row  = (rem2 >> 3) & 31;
    const int j    = rem2 & 7;
    const int o = mblk * 32 + row, k = kc * 32 + kq * 8 + j;
    float v = 0.f;
    if (k < a.K[ci]) {
        if (o < a.O1[ci])
            v = a.src[ci][(size_t)o * a.K[ci] + k];
        else if (o >= a.O2B[ci] && o - a.O2B[ci] < a.O2[ci])
            v = a.src2[ci][(size_t)(o - a.O2B[ci]) * a.K[ci] + k] * a.scale2[ci];
    }
    unsigned short h, l;
    split_bf16(v, h, l);
    a.hi[ci][idx] = h; a.lo[ci][idx] = l;
}

// ---------------------------------------------------------------------------
// Transpose + split: fp32 [C][HW] -> blocked transposed-quad bf16 hi/lo
// [b][strip(49)][kc][kq(4)][256 rows][8 shorts].  grid (392, KC, B), block 256.
// ---------------------------------------------------------------------------
__global__ __launch_bounds__(256) void tsplit_k(
    const float* __restrict__ src, size_t bstride, int C, int KC,
    unsigned short* __restrict__ hi, unsigned short* __restrict__ lo)
{
    __shared__ __align__(16) float t[32][36];
    const int b   = blockIdx.z;
    const int hw0 = blockIdx.x * 32;
    const int kc  = blockIdx.y;
    const int c0  = kc * 32;
    const int tid = threadIdx.x;

    {
        const int cl = tid >> 3, hq = (tid & 7) * 4;
        const int c  = c0 + cl;
        float4 v = make_float4(0.f, 0.f, 0.f, 0.f);
        if (c < C)
            v = *(const float4*)(src + (size_t)b * bstride + (size_t)c * HW + hw0 + hq);
        *(float4*)&t[cl][hq] = v;
    }
    __syncthreads();

    const int hl = tid >> 3, cq = (tid & 7) * 4;
    float v0 = t[cq + 0][hl], v1 = t[cq + 1][hl], v2 = t[cq + 2][hl], v3 = t[cq + 3][hl];
    ushort4 h4, l4;
    split_bf16(v0, h4.x, l4.x);
    split_bf16(v1, h4.y, l4.y);
    split_bf16(v2, h4.z, l4.z);
    split_bf16(v3, h4.w, l4.w);
    const int ns = hw0 >> 8, r = (hw0 & 255) + hl;
    const int kq = cq >> 3, j0 = cq & 7;
    const size_t base = (((size_t)b * 49 + ns) * KC + kc) * 8192
                        + (size_t)kq * 2048 + (size_t)r * 8 + j0;
    *(ushort4*)(hi + base) = h4;
    *(ushort4*)(lo + base) = l4;
}

// ---------------------------------------------------------------------------
// Split-bf16 MFMA GEMM: LDS-staged, conflict-free transposed-quad layout,
// register prefetch of chunk k+1 across the compute+barriers (R9's win).
// Block tile: M=32 (2 m-tiles) x N=256; 4 waves; 36KB LDS -> 4 blocks/CU.
// XCD swizzle keeps all m-blocks of an n-strip on one XCD (B L2-resident).
// fp32 out: o<OA -> outA; o in [obase,obase+OB) -> outB[o-obase].
// mode 2: tanh+res, 3: (tanh+res)*mul — applied only for o<Ovalid.
// grid (per_m*56, B), block 256.
// ---------------------------------------------------------------------------
template <int KP>
__global__ __launch_bounds__(256) void gemm_k(
    const unsigned short* __restrict__ bt_hi, const unsigned short* __restrict__ bt_lo,
    const unsigned short* __restrict__ w_hi,  const unsigned short* __restrict__ w_lo,
    int per_m,
    float* __restrict__ outA, int OA, size_t oa_bstride,
    float* __restrict__ outB, int OB, size_t ob_bstride, int obase,
    int mode, int Ovalid,
    const float* __restrict__ res, size_t res_bstride,
    const float* __restrict__ mul, size_t mul_bstride)
{
    constexpr int KC = KP / 32;
    __shared__ __align__(16) unsigned short Bh_s[8192];   // [kq][256][8]
    __shared__ __align__(16) unsigned short Bl_s[8192];
    __shared__ __align__(16) unsigned short Ah_s[1024];   // [kq][32][8]
    __shared__ __align__(16) unsigned short Al_s[1024];

    const int b   = blockIdx.y;
    const int bx  = blockIdx.x;
    const int xcd = bx & 7, t = bx >> 3;
    const int m   = t % per_m;
    const int ns  = (t / per_m) * 8 + xcd;
    if (ns >= 49) return;

    const int tid  = threadIdx.x;
    const int wv   = tid >> 6, lane = tid & 63;
    const int m16  = lane & 15, quad = lane >> 4;
    const int mbase = m * 32;
    const int nbase = ns * 256 + wv * 64;

    const unsigned short* Bh_g = bt_hi + ((size_t)b * 49 + ns) * KC * 8192;
    const unsigned short* Bl_g = bt_lo + ((size_t)b * 49 + ns) * KC * 8192;
    const unsigned short* Ah_g = w_hi + (size_t)m * KC * 1024;
    const unsigned short* Al_g = w_lo + (size_t)m * KC * 1024;

    f4v acc[2][4];
#pragma unroll
    for (int mt = 0; mt < 2; ++mt)
#pragma unroll
        for (int f = 0; f < 4; ++f) acc[mt][f] = (f4v){0.f, 0.f, 0.f, 0.f};

    s8v rB[8], rA;
    // ---- load chunk 0 into regs, store to LDS ----
#pragma unroll
    for (int j = 0; j < 4; ++j) {
        rB[j]     = *(const s8v*)(Bh_g + (size_t)(j * 256 + tid) * 8);
        rB[4 + j] = *(const s8v*)(Bl_g + (size_t)(j * 256 + tid) * 8);
    }
    rA = (tid < 128) ? *(const s8v*)(Ah_g + (size_t)tid * 8)
                     : *(const s8v*)(Al_g + (size_t)(tid - 128) * 8);
#pragma unroll
    for (int j = 0; j < 4; ++j) {
        *(s8v*)(Bh_s + (j * 256 + tid) * 8) = rB[j];
        *(s8v*)(Bl_s + (j * 256 + tid) * 8) = rB[4 + j];
    }
    if (tid < 128) *(s8v*)(Ah_s + tid * 8) = rA;
    else           *(s8v*)(Al_s + (tid - 128) * 8) = rA;
    __syncthreads();

#pragma unroll
    for (int kc = 0; kc < KC; ++kc) {
        // prefetch next chunk into registers (in flight behind MFMAs + barrier)
        if (kc + 1 < KC) {
            const unsigned short* bh = Bh_g + (size_t)(kc + 1) * 8192;
            const unsigned short* bl = Bl_g + (size_t)(kc + 1) * 8192;
#pragma unroll
            for (int j = 0; j < 4; ++j) {
                rB[j]     = *(const s8v*)(bh + (size_t)(j * 256 + tid) * 8);
                rB[4 + j] = *(const s8v*)(bl + (size_t)(j * 256 + tid) * 8);
            }
            rA = (tid < 128)
                ? *(const s8v*)(Ah_g + (size_t)(kc + 1) * 1024 + (size_t)tid * 8)
                : *(const s8v*)(Al_g + (size_t)(kc + 1) * 1024 + (size_t)(tid - 128) * 8);
        }
        // compute from LDS (conflict-free: contiguous 256B per quad-plane)
#pragma unroll
        for (int mt = 0; mt < 2; ++mt) {
            s8v ah = *(const s8v*)(Ah_s + (quad * 32 + mt * 16 + m16) * 8);
            s8v al = *(const s8v*)(Al_s + (quad * 32 + mt * 16 + m16) * 8);
#pragma unroll
            for (int f = 0; f < 4; ++f) {
                const int row = wv * 64 + f * 16 + m16;
                s8v bh = *(const s8v*)(Bh_s + (quad * 256 + row) * 8);
                s8v bl = *(const s8v*)(Bl_s + (quad * 256 + row) * 8);
                acc[mt][f] = __builtin_amdgcn_mfma_f32_16x16x32_bf16(ah, bh, acc[mt][f], 0, 0, 0);
                acc[mt][f] = __builtin_amdgcn_mfma_f32_16x16x32_bf16(al, bh, acc[mt][f], 0, 0, 0);
                acc[mt][f] = __builtin_amdgcn_mfma_f32_16x16x32_bf16(ah, bl, acc[mt][f], 0, 0, 0);
            }
        }
        __syncthreads();
        if (kc + 1 < KC) {
#pragma unroll
            for (int j = 0; j < 4; ++j) {
                *(s8v*)(Bh_s + (j * 256 + tid) * 8) = rB[j];
                *(s8v*)(Bl_s + (j * 256 + tid) * 8) = rB[4 + j];
            }
            if (tid < 128) *(s8v*)(Ah_s + tid * 8) = rA;
            else           *(s8v*)(Al_s + (tid - 128) * 8) = rA;
            __syncthreads();
        }
    }

    // ---- epilogue ----
#pragma unroll
    for (int mt = 0; mt < 2; ++mt) {
#pragma unroll
        for (int f = 0; f < 4; ++f) {
            const int n = nbase + f * 16 + m16;
#pragma unroll
            for (int r = 0; r < 4; ++r) {
                const int o = mbase + mt * 16 + quad * 4 + r;
                float v = acc[mt][f][r];
                if (mode == 2) {
                    if (o < Ovalid)
                        v = tanhf(v) + res[(size_t)b * res_bstride + (size_t)o * HW + n];
                } else if (mode == 3) {
                    if (o < Ovalid)
                        v = (tanhf(v) + res[(size_t)b * res_bstride + (size_t)o * HW + n])
                            * mul[(size_t)b * mul_bstride + (size_t)o * HW + n];
                }
                if (o < OA) {
                    outA[(size_t)b * oa_bstride + (size_t)o * HW + n] = v;
                } else if (o >= obase && o - obase < OB) {
                    outB[(size_t)b * ob_bstride + (size_t)(o - obase) * HW + n] = v;
                }
            }
        }
    }
}

// ---------------------------------------------------------------------------
// 16x16 block mean-pool 112x112 -> 7x7.  grid (C, B), block 64 (49 active).
// ---------------------------------------------------------------------------
__global__ __launch_bounds__(64) void pool_k(
    const float* __restrict__ ctx, float* __restrict__ pooled, int C)
{
    const int c = blockIdx.x, b = blockIdx.y, t = threadIdx.x;
    if (t >= 49) return;
    const int ph = t / 7, pw = t % 7;
    const float* src = ctx + ((size_t)b * C + c) * HW;
    float sum = 0.f;
    for (int i = 0; i < 16; ++i) {
        const float* row = src + (ph * 16 + i) * W_IMG + pw * 16;
        for (int j = 0; j < 16; ++j) sum += row[j];
    }
    pooled[((size_t)b * C + c) * 49 + t] = sum * (1.0f / 256.0f);
}

// ---------------------------------------------------------------------------
// key[b,o,l] = sum_c wk[o,c] * pooled[b,c,l].  grid (O, B), block 64.
// ---------------------------------------------------------------------------
__global__ __launch_bounds__(64) void keygemm_k(
    const float* __restrict__ pooled, const float* __restrict__ wk,
    float* __restrict__ key, int K, int O)
{
    const int o = blockIdx.x, b = blockIdx.y, l = threadIdx.x;
    if (l >= 49) return;
    float s = 0.f;
    for (int c = 0; c < K; ++c)
        s += wk[(size_t)o * K + c] * pooled[((size_t)b * K + c) * 49 + l];
    key[((size_t)b * O + o) * 49 + l] = s;
}

// ---------------------------------------------------------------------------
// Attention scores + double softmax.  attn layout [b][g][18][HW] (tap-major).
// grid (49, 2, B), block 256.
// ---------------------------------------------------------------------------
__global__ __launch_bounds__(256) void attn_k(
    const float* __restrict__ q, const float* __restrict__ key,
    const float* __restrict__ wp, const float* __restrict__ pb,
    float* __restrict__ attn, int hd)
{
    __shared__ float klds[86 * 52];
    __shared__ float plds[18 * 52];
    __shared__ float pblds[18];

    const int b = blockIdx.z, g = blockIdx.y, tid = threadIdx.x;

    for (int idx = tid; idx < hd * 49; idx += 256) {
        int c = idx / 49, l = idx - c * 49;
        klds[c * 52 + l] = key[((size_t)(b * 2 + g) * hd + c) * 49 + l];
    }
    for (int idx = tid; idx < hd * 3; idx += 256) {
        int c = idx / 3;
        klds[c * 52 + 49 + (idx - c * 3)] = 0.f;
    }
    for (int idx = tid; idx < 18 * 49; idx += 256) {
        int o = idx / 49, l = idx - o * 49;
        plds[o * 52 + l] = wp[o * 49 + l];
    }
    for (int idx = tid; idx < 18 * 3; idx += 256) {
        int o = idx / 3;
        plds[o * 52 + 49 + (idx - o * 3)] = 0.f;
    }
    if (tid < 18) pblds[tid] = pb[tid];
    __syncthreads();

    const int hw = blockIdx.x * 256 + tid;

    float4 s[13];
#pragma unroll
    for (int t = 0; t < 13; ++t) s[t] = make_float4(0.f, 0.f, 0.f, 0.f);

    const float* qp = q + (size_t)(b * 2 + g) * hd * HW + hw;
    for (int c = 0; c < hd; ++c) {
        float qv = qp[(size_t)c * HW];
        const float4* kr = (const float4*)(klds + c * 52);
#pragma unroll
        for (int t = 0; t < 13; ++t) {
            float4 kv = kr[t];
            s[t].x += qv * kv.x; s[t].y += qv * kv.y;
            s[t].z += qv * kv.z; s[t].w += qv * kv.w;
        }
    }

    float e[18];
#pragma unroll
    for (int o = 0; o < 18; ++o) {
        const float4* pr = (const float4*)(plds + o * 52);
        float4 a = make_float4(0.f, 0.f, 0.f, 0.f);
#pragma unroll
        for (int t = 0; t < 13; ++t) {
            float4 pv = pr[t];
            a.x += s[t].x * pv.x; a.y += s[t].y * pv.y;
            a.z += s[t].z * pv.z; a.w += s[t].w * pv.w;
        }
        e[o] = pblds[o] + a.x + a.y + a.z + a.w;
    }

    float* outp = attn + (size_t)(b * 2 + g) * 18 * HW + hw;
#pragma unroll
    for (int half = 0; half < 2; ++half) {
        int base = half * 9;
        float m = e[base];
#pragma unroll
        for (int k = 1; k < 9; ++k) m = fmaxf(m, e[base + k]);
        float sum = 0.f, ex[9];
#pragma unroll
        for (int k = 0; k < 9; ++k) { ex[k] = expf(e[base + k] - m); sum += ex[k]; }
        float inv = 1.0f / sum;
#pragma unroll
        for (int k = 0; k < 9; ++k) outp[(size_t)(base + k) * HW] = ex[k] * inv;
    }
}

// ---------------------------------------------------------------------------
// Dynamic depthwise 3x3 mix, tap-major attn layout. grid (49, C, B), block 256.
// ---------------------------------------------------------------------------
__global__ __launch_bounds__(256) void dyndw_k(
    const float* __restrict__ x, const float* __restrict__ attn,
    float* __restrict__ y, int C, int C_half, int hd, size_t x_bstride)
{
    const int b = blockIdx.z, c = blockIdx.y;
    const int hw = blockIdx.x * 256 + threadIdx.x;
    const int h = hw / W_IMG, w = hw - h * W_IMG;

    const int half = c / C_half;
    const int g = (c - half * C_half) / hd;

    const float* ap = attn + ((size_t)(b * 2 + g) * 18 + half * 9) * HW + hw;
    float a[9];
#pragma unroll
    for (int k = 0; k < 9; ++k) a[k] = ap[(size_t)k * HW];

    const float* xp = x + (size_t)b * x_bstride + (size_t)c * HW;
    float s = 0.f;
#pragma unroll
    for (int i = 0; i < 3; ++i) {
        int hh = h + i - 1;
#pragma unroll
        for (int j = 0; j < 3; ++j) {
            int ww = w + j - 1;
            float v = (hh >= 0 && hh < 112 && ww >= 0 && ww < 112)
                          ? xp[hh * W_IMG + ww] : 0.f;
            s += v * a[i * 3 + j];
        }
    }
    y[((size_t)b * C + c) * HW + hw] = s;
}

// ---------------------------------------------------------------------------
extern "C" void kernel_launch(void* const* d_in, const int* in_sizes, int n_in,
                              void* d_out, int out_size, void* d_ws, size_t ws_size,
                              hipStream_t stream) {
    const float* x      = (const float*)d_in[0];
    const float* pin_w  = (const float*)d_in[1];
    const float* ctx_w  = (const float*)d_in[2];
    const float* ctx1_w = (const float*)d_in[3];
    const float* ctx2_w = (const float*)d_in[4];
    const float* pout_w = (const float*)d_in[5];
    const float* cm0_q  = (const float*)d_in[6];
    const float* cm0_k  = (const float*)d_in[7];
    const float* cm0_p  = (const float*)d_in[8];
    const float* cm0_pb = (const float*)d_in[9];
    const float* cm0_o  = (const float*)d_in[10];
    const float* cm1_q  = (const float*)d_in[11];
    const float* cm1_k  = (const float*)d_in[12];
    const float* cm1_p  = (const float*)d_in[13];
    const float* cm1_pb = (const float*)d_in[14];
    const float* cm1_o  = (const float*)d_in[15];
    const float* cm2_q  = (const float*)d_in[16];
    const float* cm2_k  = (const float*)d_in[17];
    const float* cm2_p  = (const float*)d_in[18];
    const float* cm2_pb = (const float*)d_in[19];
    const float* cm2_o  = (const float*)d_in[20];
    float* out = (float*)d_out;

    float* ws = (float*)d_ws;
    // ---- fp32 region (floats, ends 35449568 = 141.8 MB) ----
    float* x_in  = ws;                          // [2,344,HW]
    float* x1p   = ws;                          // [2,172,HW] (after x_in dead)
    float* y0    = ws + 8630272;                // [2,344,HW]
    float* y1    = ws + 8630272;                // [2,172,HW]
    float* prod  = ws + 8630272;                // [2,172,HW] (after y1 dead)
    float* y2    = ws + 12945408;               // [2,172,HW]
    float* x_dw  = ws + 17260544;               // [2,344,HW]
    float* ctxb  = ws + 25890816;               // [2,86,HW]
    float* ctx1  = ws + 28048384;               // [2,43,HW]
    float* ctx2  = ws + 29127168;               // [2,43,HW]
    float* q0    = ws + 30205952;               // [2,172,HW]
    float* q1    = ws + 30205952;               // [2,86,HW]
    float* q2    = ws + 32363520;               // [2,86,HW]
    float* attnb = ws + 34521088;               // [2,2,18,HW]
    float* pooled= ws + 35424256;               // [2,86,49]
    float* keyb  = ws + 35432704;               // [2,172,49]
    // ---- bf16 region (ushorts; ends 40953856 sh = 81.9 MB; total ws 223.7 MB) ----
    unsigned short* ub = (unsigned short*)(ws + 35449568);
    // conv entries: 0 pin | 1 ctx+q0 | 2 cm0_o(restacked 172/192) | 3 ctx1+q1
    //               4 ctx2+q2 | 5 cm1_o | 6 cm2_o | 7 pout   (Mp mult of 32)
    static const int WOFF[8] = {0, 45056, 247808, 518144, 579584, 641024, 714752, 788480};
    static const int WO1[8]  = {344, 86, 172, 43, 43, 172, 172, 64};
    static const int WO2[8]  = {0, 172, 172, 86, 86, 0, 0, 0};
    static const int O2B[8]  = {352, 86, 192, 43, 43, 192, 192, 64};
    static const int WK[8]   = {64, 344, 344, 172, 172, 172, 172, 172};
    static const int WKP[8]  = {64, 352, 352, 192, 192, 192, 192, 192};
    static const int WMP[8]  = {352, 288, 384, 160, 160, 192, 192, 64};
    // X_t planes (weights end at 813056)
    unsigned short* xt_hi   = ub + 813056;      // [2][49][2][8192]
    unsigned short* xt_lo   = ub + 2418688;     // end 4024320
    // bigA slab [2][49][11][8192]; serially reused: xint -> yt -> pt(KC=6)
    unsigned short* bigA_hi = ub + 4024320;
    unsigned short* bigA_lo = ub + 12855296;    // end 21686272
    unsigned short* x1t_hi  = ub + 21686272;    // [2][49][6][8192]; later y1t
    unsigned short* x1t_lo  = ub + 26503168;    // end 31320064
    unsigned short* x2t_hi  = ub + 31320064;    // later y2t
    unsigned short* x2t_lo  = ub + 36136960;    // end 40953856

    const float sc0 = 1.0f / sqrtf(86.0f);
    const float sc1 = 1.0f / sqrtf(43.0f);
    const size_t BS344 = (size_t)344 * HW, BS172 = (size_t)172 * HW,
                 BS86 = (size_t)86 * HW, BS64 = (size_t)64 * HW, BS43 = (size_t)43 * HW;

    // ---- 0. split/restack all weights (q-scales folded in, blocked layout) ----
    WSplitArgs wa;
    const float* wsrc1[8] = {pin_w, ctx_w, cm0_o, ctx1_w, ctx2_w, cm1_o, cm2_o, pout_w};
    const float* wsrc2[8] = {nullptr, cm0_q, cm0_o + (size_t)172 * 344, cm1_q, cm2_q,
                             nullptr, nullptr, nullptr};
    const float wsc2[8]   = {1.f, sc0, 1.f, sc1, sc1, 1.f, 1.f, 1.f};
    for (int i = 0; i < 8; ++i) {
        wa.src[i] = wsrc1[i]; wa.src2[i] = wsrc2[i];
        wa.hi[i]  = ub + WOFF[i];
        wa.lo[i]  = ub + WOFF[i] + WMP[i] * WKP[i];
        wa.O1[i] = WO1[i]; wa.O2[i] = WO2[i]; wa.O2B[i] = O2B[i];
        wa.K[i] = WK[i]; wa.Kp[i] = WKP[i];
        wa.MpKp[i] = WMP[i] * WKP[i];
        wa.scale2[i] = wsc2[i];
    }
    wsplit_k<<<dim3(528, 8), 256, 0, stream>>>(wa);

#define WHI(CI) (ub + WOFF[CI])
#define WLO(CI) (ub + WOFF[CI] + WMP[CI] * WKP[CI])
#define GRID(CI) dim3((WMP[CI] / 32) * 56, B_SZ)

    // ---- pin: x_in = pin_w @ x ----
    tsplit_k<<<dim3(392, 2, B_SZ), 256, 0, stream>>>(x, BS64, 64, 2, xt_hi, xt_lo);
    gemm_k<64><<<GRID(0), 256, 0, stream>>>(
        xt_hi, xt_lo, WHI(0), WLO(0), WMP[0] / 32,
        x_in, 344, BS344, nullptr, 0, 0, 352, 0, 344,
        nullptr, 0, nullptr, 0);
    tsplit_k<<<dim3(392, 11, B_SZ), 256, 0, stream>>>(x_in, BS344, 344, 11, bigA_hi, bigA_lo);

    // ---- contmix0: fused ctx_dw + q0 ----
    gemm_k<352><<<GRID(1), 256, 0, stream>>>(
        bigA_hi, bigA_lo, WHI(1), WLO(1), WMP[1] / 32,
        ctxb, 86, BS86, q0, 172, BS172, 86, 0, 258,
        nullptr, 0, nullptr, 0);
    pool_k<<<dim3(86, B_SZ), dim3(64), 0, stream>>>(ctxb, pooled, 86);
    keygemm_k<<<dim3(172, B_SZ), dim3(64), 0, stream>>>(pooled, cm0_k, keyb, 86, 172);
    attn_k<<<dim3(49, 2, B_SZ), dim3(256), 0, stream>>>(q0, keyb, cm0_p, cm0_pb, attnb, 86);
    dyndw_k<<<dim3(49, 344, B_SZ), dim3(256), 0, stream>>>(x_in, attnb, y0, 344, 172, 86, BS344);
    tsplit_k<<<dim3(392, 11, B_SZ), 256, 0, stream>>>(y0, BS344, 344, 11, bigA_hi, bigA_lo);
    // x_dw = cm0_o @ y  (restacked: rows 0..172 -> x1, 192..364 -> x2)
    gemm_k<352><<<GRID(2), 256, 0, stream>>>(
        bigA_hi, bigA_lo, WHI(2), WLO(2), WMP[2] / 32,
        x_dw, 172, BS344, x_dw + BS172, 172, BS344, 192, 0, 384,
        nullptr, 0, nullptr, 0);

    // ---- transpose halves of x_dw ----
    tsplit_k<<<dim3(392, 6, B_SZ), 256, 0, stream>>>(x_dw, BS344, 172, 6, x1t_hi, x1t_lo);
    tsplit_k<<<dim3(392, 6, B_SZ), 256, 0, stream>>>(x_dw + BS172, BS344, 172, 6, x2t_hi, x2t_lo);

    // ---- contmix1 on x1 ----
    gemm_k<192><<<GRID(3), 256, 0, stream>>>(
        x1t_hi, x1t_lo, WHI(3), WLO(3), WMP[3] / 32,
        ctx1, 43, BS43, q1, 86, BS86, 43, 0, 129,
        nullptr, 0, nullptr, 0);
    pool_k<<<dim3(43, B_SZ), dim3(64), 0, stream>>>(ctx1, pooled, 43);
    keygemm_k<<<dim3(86, B_SZ), dim3(64), 0, stream>>>(pooled, cm1_k, keyb, 43, 86);
    attn_k<<<dim3(49, 2, B_SZ), dim3(256), 0, stream>>>(q1, keyb, cm1_p, cm1_pb, attnb, 43);
    dyndw_k<<<dim3(49, 172, B_SZ), dim3(256), 0, stream>>>(x_dw, attnb, y1, 172, 86, 43, BS344);
    tsplit_k<<<dim3(392, 6, B_SZ), 256, 0, stream>>>(y1, BS172, 172, 6, x1t_hi, x1t_lo);
    // x1p = tanh(cm1_o @ y1) + x1
    gemm_k<192><<<GRID(5), 256, 0, stream>>>(
        x1t_hi, x1t_lo, WHI(5), WLO(5), WMP[5] / 32,
        x1p, 172, BS172, nullptr, 0, 0, 192, 2, 172,
        x_dw, BS344, nullptr, 0);

    // ---- contmix2 on x2 ----
    gemm_k<192><<<GRID(4), 256, 0, stream>>>(
        x2t_hi, x2t_lo, WHI(4), WLO(4), WMP[4] / 32,
        ctx2, 43, BS43, q2, 86, BS86, 43, 0, 129,
        nullptr, 0, nullptr, 0);
    pool_k<<<dim3(43, B_SZ), dim3(64), 0, stream>>>(ctx2, pooled, 43);
    keygemm_k<<<dim3(86, B_SZ), dim3(64), 0, stream>>>(pooled, cm2_k, keyb, 43, 86);
    attn_k<<<dim3(49, 2, B_SZ), dim3(256), 0, stream>>>(q2, keyb, cm2_p, cm2_pb, attnb, 43);
    dyndw_k<<<dim3(49, 172, B_SZ), dim3(256), 0, stream>>>(x_dw + BS172, attnb, y2, 172, 86, 43, BS344);
    tsplit_k<<<dim3(392, 6, B_SZ), 256, 0, stream>>>(y2, BS172, 172, 6, x2t_hi, x2t_lo);
    // prod = (tanh(cm2_o @ y2) + x2) * x1p
    gemm_k<192><<<GRID(6), 256, 0, stream>>>(
        x2t_hi, x2t_lo, WHI(6), WLO(6), WMP[6] / 32,
        prod, 172, BS172, nullptr, 0, 0, 192, 3, 172,
        x_dw + BS172, BS344, x1p, BS172);

    // ---- pout ----
    tsplit_k<<<dim3(392, 6, B_SZ), 256, 0, stream>>>(prod, BS172, 172, 6, bigA_hi, bigA_lo);
    gemm_k<192><<<GRID(7), 256, 0, stream>>>(
        bigA_hi, bigA_lo, WHI(7), WLO(7), WMP[7] / 32,
        out, 64, BS64, nullptr, 0, 0, 64, 0, 64,
        nullptr, 0, nullptr, 0);

#undef WHI
#undef WLO
#undef GRID
}

// Round 13
// 532.134 us; speedup vs baseline: 1.2384x; 1.0432x over previous
//
#include <hip/hip_runtime.h>
#include <math.h>

#define HW 12544      // 112*112
#define W_IMG 112
#define B_SZ 2

typedef __attribute__((ext_vector_type(8))) short s8v;   // 8 bf16 (4 VGPRs)
typedef __attribute__((ext_vector_type(4))) float f4v;   // MFMA acc

__device__ __forceinline__ void split_bf16(float x, unsigned short& h, unsigned short& l) {
    unsigned u  = __float_as_uint(x);
    unsigned hb = (u + 0x7FFFu + ((u >> 16) & 1u)) >> 16;
    float hf    = __uint_as_float(hb << 16);
    float r     = x - hf;
    unsigned ur = __float_as_uint(r);
    unsigned lb = (ur + 0x7FFFu + ((ur >> 16) & 1u)) >> 16;
    h = (unsigned short)hb; l = (unsigned short)lb;
}

// ---------------------------------------------------------------------------
// Weight split -> blocked transposed-quad bf16 hi/lo:
// [mblk(32 rows)][kc][kq(4)][32 rows][8 shorts].
// Rows [0,O1) from src, rows [o2base, o2base+O2) from src2 (scaled), else 0.
// ---------------------------------------------------------------------------
struct WSplitArgs {
    const float* src[8];
    const float* src2[8];
    unsigned short* hi[8];
    unsigned short* lo[8];
    int O1[8]; int O2[8]; int O2B[8]; int K[8]; int Kp[8]; int MpKp[8];
    float scale2[8];
};

__global__ __launch_bounds__(256) void wsplit_k(WSplitArgs a) {
    const int ci  = blockIdx.y;
    const int idx = blockIdx.x * 256 + threadIdx.x;
    if (idx >= a.MpKp[ci]) return;
    const int Kp   = a.Kp[ci];
    const int blk  = 32 * Kp;              // shorts per m-block = KC*1024
    const int mblk = idx / blk;
    const int rem  = idx - mblk * blk;
    const int kc   = rem >> 10;            // /1024
    const int rem2 = rem & 1023;
    const int kq   = rem2 >> 8;            // /256
    const int row  = (rem2 >> 3) & 31;
    const int j    = rem2 & 7;
    const int o = mblk * 32 + row, k = kc * 32 + kq * 8 + j;
    float v = 0.f;
    if (k < a.K[ci]) {
        if (o < a.O1[ci])
            v = a.src[ci][(size_t)o * a.K[ci] + k];
        else if (o >= a.O2B[ci] && o - a.O2B[ci] < a.O2[ci])
            v = a.src2[ci][(size_t)(o - a.O2B[ci]) * a.K[ci] + k] * a.scale2[ci];
    }
    unsigned short h, l;
    split_bf16(v, h, l);
    a.hi[ci][idx] = h; a.lo[ci][idx] = l;
}

// ---------------------------------------------------------------------------
// Transpose + split: fp32 [C][HW] -> blocked transposed-quad bf16 hi/lo
// [b][strip(49)][kc][kq(4)][256 rows][8 shorts].  grid (392, KC, B), block 256.
// ---------------------------------------------------------------------------
__global__ __launch_bounds__(256) void tsplit_k(
    const float* __restrict__ src, size_t bstride, int C, int KC,
    unsigned short* __restrict__ hi, unsigned short* __restrict__ lo)
{
    __shared__ __align__(16) float t[32][36];
    const int b   = blockIdx.z;
    const int hw0 = blockIdx.x * 32;
    const int kc  = blockIdx.y;
    const int c0  = kc * 32;
    const int tid = threadIdx.x;

    {
        const int cl = tid >> 3, hq = (tid & 7) * 4;
        const int c  = c0 + cl;
        float4 v = make_float4(0.f, 0.f, 0.f, 0.f);
        if (c < C)
            v = *(const float4*)(src + (size_t)b * bstride + (size_t)c * HW + hw0 + hq);
        *(float4*)&t[cl][hq] = v;
    }
    __syncthreads();

    const int hl = tid >> 3, cq = (tid & 7) * 4;
    float v0 = t[cq + 0][hl], v1 = t[cq + 1][hl], v2 = t[cq + 2][hl], v3 = t[cq + 3][hl];
    ushort4 h4, l4;
    split_bf16(v0, h4.x, l4.x);
    split_bf16(v1, h4.y, l4.y);
    split_bf16(v2, h4.z, l4.z);
    split_bf16(v3, h4.w, l4.w);
    const int ns = hw0 >> 8, r = (hw0 & 255) + hl;
    const int kq = cq >> 3, j0 = cq & 7;
    const size_t base = (((size_t)b * 49 + ns) * KC + kc) * 8192
                        + (size_t)kq * 2048 + (size_t)r * 8 + j0;
    *(ushort4*)(hi + base) = h4;
    *(ushort4*)(lo + base) = l4;
}

// ---------------------------------------------------------------------------
// Split-bf16 MFMA GEMM: LDS-staged, conflict-free transposed-quad layout,
// register prefetch of chunk k+1 across the compute+barriers.
// Block tile: M=32 (2 m-tiles) x N=256; 4 waves; 36KB LDS -> 4 blocks/CU.
// XCD swizzle keeps all m-blocks of an n-strip on one XCD (B L2-resident).
// fp32 out: o<OA -> outA; o in [obase,obase+OB) -> outB[o-obase].
// mode 2: tanh+res, 3: (tanh+res)*mul — applied only for o<Ovalid.
// grid (per_m*56, B), block 256.
// ---------------------------------------------------------------------------
template <int KP>
__global__ __launch_bounds__(256) void gemm_k(
    const unsigned short* __restrict__ bt_hi, const unsigned short* __restrict__ bt_lo,
    const unsigned short* __restrict__ w_hi,  const unsigned short* __restrict__ w_lo,
    int per_m,
    float* __restrict__ outA, int OA, size_t oa_bstride,
    float* __restrict__ outB, int OB, size_t ob_bstride, int obase,
    int mode, int Ovalid,
    const float* __restrict__ res, size_t res_bstride,
    const float* __restrict__ mul, size_t mul_bstride)
{
    constexpr int KC = KP / 32;
    __shared__ __align__(16) unsigned short Bh_s[8192];   // [kq][256][8]
    __shared__ __align__(16) unsigned short Bl_s[8192];
    __shared__ __align__(16) unsigned short Ah_s[1024];   // [kq][32][8]
    __shared__ __align__(16) unsigned short Al_s[1024];

    const int b   = blockIdx.y;
    const int bx  = blockIdx.x;
    const int xcd = bx & 7, t = bx >> 3;
    const int m   = t % per_m;
    const int ns  = (t / per_m) * 8 + xcd;
    if (ns >= 49) return;

    const int tid  = threadIdx.x;
    const int wv   = tid >> 6, lane = tid & 63;
    const int m16  = lane & 15, quad = lane >> 4;
    const int mbase = m * 32;
    const int nbase = ns * 256 + wv * 64;

    const unsigned short* Bh_g = bt_hi + ((size_t)b * 49 + ns) * KC * 8192;
    const unsigned short* Bl_g = bt_lo + ((size_t)b * 49 + ns) * KC * 8192;
    const unsigned short* Ah_g = w_hi + (size_t)m * KC * 1024;
    const unsigned short* Al_g = w_lo + (size_t)m * KC * 1024;

    f4v acc[2][4];
#pragma unroll
    for (int mt = 0; mt < 2; ++mt)
#pragma unroll
        for (int f = 0; f < 4; ++f) acc[mt][f] = (f4v){0.f, 0.f, 0.f, 0.f};

    s8v rB[8], rA;
    // ---- load chunk 0 into regs, store to LDS ----
#pragma unroll
    for (int j = 0; j < 4; ++j) {
        rB[j]     = *(const s8v*)(Bh_g + (size_t)(j * 256 + tid) * 8);
        rB[4 + j] = *(const s8v*)(Bl_g + (size_t)(j * 256 + tid) * 8);
    }
    rA = (tid < 128) ? *(const s8v*)(Ah_g + (size_t)tid * 8)
                     : *(const s8v*)(Al_g + (size_t)(tid - 128) * 8);
#pragma unroll
    for (int j = 0; j < 4; ++j) {
        *(s8v*)(Bh_s + (j * 256 + tid) * 8) = rB[j];
        *(s8v*)(Bl_s + (j * 256 + tid) * 8) = rB[4 + j];
    }
    if (tid < 128) *(s8v*)(Ah_s + tid * 8) = rA;
    else           *(s8v*)(Al_s + (tid - 128) * 8) = rA;
    __syncthreads();

#pragma unroll
    for (int kc = 0; kc < KC; ++kc) {
        // prefetch next chunk into registers (in flight behind MFMAs + barrier)
        if (kc + 1 < KC) {
            const unsigned short* bh = Bh_g + (size_t)(kc + 1) * 8192;
            const unsigned short* bl = Bl_g + (size_t)(kc + 1) * 8192;
#pragma unroll
            for (int j = 0; j < 4; ++j) {
                rB[j]     = *(const s8v*)(bh + (size_t)(j * 256 + tid) * 8);
                rB[4 + j] = *(const s8v*)(bl + (size_t)(j * 256 + tid) * 8);
            }
            rA = (tid < 128)
                ? *(const s8v*)(Ah_g + (size_t)(kc + 1) * 1024 + (size_t)tid * 8)
                : *(const s8v*)(Al_g + (size_t)(kc + 1) * 1024 + (size_t)(tid - 128) * 8);
        }
        // compute from LDS (conflict-free: contiguous 256B per quad-plane)
#pragma unroll
        for (int mt = 0; mt < 2; ++mt) {
            s8v ah = *(const s8v*)(Ah_s + (quad * 32 + mt * 16 + m16) * 8);
            s8v al = *(const s8v*)(Al_s + (quad * 32 + mt * 16 + m16) * 8);
#pragma unroll
            for (int f = 0; f < 4; ++f) {
                const int row = wv * 64 + f * 16 + m16;
                s8v bh = *(const s8v*)(Bh_s + (quad * 256 + row) * 8);
                s8v bl = *(const s8v*)(Bl_s + (quad * 256 + row) * 8);
                acc[mt][f] = __builtin_amdgcn_mfma_f32_16x16x32_bf16(ah, bh, acc[mt][f], 0, 0, 0);
                acc[mt][f] = __builtin_amdgcn_mfma_f32_16x16x32_bf16(al, bh, acc[mt][f], 0, 0, 0);
                acc[mt][f] = __builtin_amdgcn_mfma_f32_16x16x32_bf16(ah, bl, acc[mt][f], 0, 0, 0);
            }
        }
        __syncthreads();
        if (kc + 1 < KC) {
#pragma unroll
            for (int j = 0; j < 4; ++j) {
                *(s8v*)(Bh_s + (j * 256 + tid) * 8) = rB[j];
                *(s8v*)(Bl_s + (j * 256 + tid) * 8) = rB[4 + j];
            }
            if (tid < 128) *(s8v*)(Ah_s + tid * 8) = rA;
            else           *(s8v*)(Al_s + (tid - 128) * 8) = rA;
            __syncthreads();
        }
    }

    // ---- epilogue ----
#pragma unroll
    for (int mt = 0; mt < 2; ++mt) {
#pragma unroll
        for (int f = 0; f < 4; ++f) {
            const int n = nbase + f * 16 + m16;
#pragma unroll
            for (int r = 0; r < 4; ++r) {
                const int o = mbase + mt * 16 + quad * 4 + r;
                float v = acc[mt][f][r];
                if (mode == 2) {
                    if (o < Ovalid)
                        v = tanhf(v) + res[(size_t)b * res_bstride + (size_t)o * HW + n];
                } else if (mode == 3) {
                    if (o < Ovalid)
                        v = (tanhf(v) + res[(size_t)b * res_bstride + (size_t)o * HW + n])
                            * mul[(size_t)b * mul_bstride + (size_t)o * HW + n];
                }
                if (o < OA) {
                    outA[(size_t)b * oa_bstride + (size_t)o * HW + n] = v;
                } else if (o >= obase && o - obase < OB) {
                    outB[(size_t)b * ob_bstride + (size_t)(o - obase) * HW + n] = v;
                }
            }
        }
    }
}

// ---------------------------------------------------------------------------
// FUSED dynamic depthwise 3x3 mix + bf16-split + blocked-transpose output.
// Replaces dyndw_k + tsplit_k: y fp32 never materialized.
// Block = one 256-pixel strip x 8 consecutive channels (c0 aligned 8 ->
// same kc/kq; j spans 0..7 -> each lane stores one contiguous s8v per plane).
// Channels >= C write zeros (preserves Kp zero-padding).
// grid (49, Kp/8, B), block 256.
// ---------------------------------------------------------------------------
__global__ __launch_bounds__(256) void dyndw_bt_k(
    const float* __restrict__ x, const float* __restrict__ attn,
    unsigned short* __restrict__ hi, unsigned short* __restrict__ lo,
    int C, int C_half, int hd, size_t x_bstride, int KC)
{
    const int b  = blockIdx.z, ns = blockIdx.x, tid = threadIdx.x;
    const int c0 = blockIdx.y * 8;
    const int hw = ns * 256 + tid;
    const int h = hw / W_IMG, w = hw - h * W_IMG;

    // 3x3 neighborhood offsets & validity (shared across the 8 channels)
    int off[9]; bool val[9];
#pragma unroll
    for (int i = 0; i < 3; ++i)
#pragma unroll
        for (int j = 0; j < 3; ++j) {
            const int hh = h + i - 1, ww = w + j - 1;
            val[i * 3 + j] = (hh >= 0 && hh < 112 && ww >= 0 && ww < 112);
            off[i * 3 + j] = hh * W_IMG + ww;
        }

    s8v hvv, lvv;
#pragma unroll
    for (int u = 0; u < 8; ++u) {
        const int c = c0 + u;
        float acc = 0.f;
        if (c < C) {
            const int half = c / C_half;
            const int g = (c - half * C_half) / hd;
            const float* ap = attn + ((size_t)(b * 2 + g) * 18 + half * 9) * HW + hw;
            const float* xp = x + (size_t)b * x_bstride + (size_t)c * HW;
#pragma unroll
            for (int k = 0; k < 9; ++k) {
                const float xv = val[k] ? xp[off[k]] : 0.f;
                acc += ap[(size_t)k * HW] * xv;
            }
        }
        unsigned short hs, ls;
        split_bf16(acc, hs, ls);
        hvv[u] = (short)hs; lvv[u] = (short)ls;
    }

    const int kc = c0 >> 5, kq = (c0 & 31) >> 3;
    const size_t base = (((size_t)b * 49 + ns) * KC + kc) * 8192
                        + (size_t)kq * 2048 + (size_t)tid * 8;
    *(s8v*)(hi + base) = hvv;
    *(s8v*)(lo + base) = lvv;
}

// ---------------------------------------------------------------------------
// 16x16 block mean-pool 112x112 -> 7x7.  grid (C, B), block 64 (49 active).
// ---------------------------------------------------------------------------
__global__ __launch_bounds__(64) void pool_k(
    const float* __restrict__ ctx, float* __restrict__ pooled, int C)
{
    const int c = blockIdx.x, b = blockIdx.y, t = threadIdx.x;
    if (t >= 49) return;
    const int ph = t / 7, pw = t % 7;
    const float* src = ctx + ((size_t)b * C + c) * HW;
    float sum = 0.f;
    for (int i = 0; i < 16; ++i) {
        const float* row = src + (ph * 16 + i) * W_IMG + pw * 16;
        for (int j = 0; j < 16; ++j) sum += row[j];
    }
    pooled[((size_t)b * C + c) * 49 + t] = sum * (1.0f / 256.0f);
}

// ---------------------------------------------------------------------------
// key[b,o,l] = sum_c wk[o,c] * pooled[b,c,l].  grid (O, B), block 64.
// ---------------------------------------------------------------------------
__global__ __launch_bounds__(64) void keygemm_k(
    const float* __restrict__ pooled, const float* __restrict__ wk,
    float* __restrict__ key, int K, int O)
{
    const int o = blockIdx.x, b = blockIdx.y, l = threadIdx.x;
    if (l >= 49) return;
    float s = 0.f;
    for (int c = 0; c < K; ++c)
        s += wk[(size_t)o * K + c] * pooled[((size_t)b * K + c) * 49 + l];
    key[((size_t)b * O + o) * 49 + l] = s;
}

// ---------------------------------------------------------------------------
// Attention scores + double softmax.  attn layout [b][g][18][HW] (tap-major).
// grid (49, 2, B), block 256.
// ---------------------------------------------------------------------------
__global__ __launch_bounds__(256) void attn_k(
    const float* __restrict__ q, const float* __restrict__ key,
    const float* __restrict__ wp, const float* __restrict__ pb,
    float* __restrict__ attn, int hd)
{
    __shared__ float klds[86 * 52];
    __shared__ float plds[18 * 52];
    __shared__ float pblds[18];

    const int b = blockIdx.z, g = blockIdx.y, tid = threadIdx.x;

    for (int idx = tid; idx < hd * 49; idx += 256) {
        int c = idx / 49, l = idx - c * 49;
        klds[c * 52 + l] = key[((size_t)(b * 2 + g) * hd + c) * 49 + l];
    }
    for (int idx = tid; idx < hd * 3; idx += 256) {
        int c = idx / 3;
        klds[c * 52 + 49 + (idx - c * 3)] = 0.f;
    }
    for (int idx = tid; idx < 18 * 49; idx += 256) {
        int o = idx / 49, l = idx - o * 49;
        plds[o * 52 + l] = wp[o * 49 + l];
    }
    for (int idx = tid; idx < 18 * 3; idx += 256) {
        int o = idx / 3;
        plds[o * 52 + 49 + (idx - o * 3)] = 0.f;
    }
    if (tid < 18) pblds[tid] = pb[tid];
    __syncthreads();

    const int hw = blockIdx.x * 256 + tid;

    float4 s[13];
#pragma unroll
    for (int t = 0; t < 13; ++t) s[t] = make_float4(0.f, 0.f, 0.f, 0.f);

    const float* qp = q + (size_t)(b * 2 + g) * hd * HW + hw;
    for (int c = 0; c < hd; ++c) {
        float qv = qp[(size_t)c * HW];
        const float4* kr = (const float4*)(klds + c * 52);
#pragma unroll
        for (int t = 0; t < 13; ++t) {
            float4 kv = kr[t];
            s[t].x += qv * kv.x; s[t].y += qv * kv.y;
            s[t].z += qv * kv.z; s[t].w += qv * kv.w;
        }
    }

    float e[18];
#pragma unroll
    for (int o = 0; o < 18; ++o) {
        const float4* pr = (const float4*)(plds + o * 52);
        float4 a = make_float4(0.f, 0.f, 0.f, 0.f);
#pragma unroll
        for (int t = 0; t < 13; ++t) {
            float4 pv = pr[t];
            a.x += s[t].x * pv.x; a.y += s[t].y * pv.y;
            a.z += s[t].z * pv.z; a.w += s[t].w * pv.w;
        }
        e[o] = pblds[o] + a.x + a.y + a.z + a.w;
    }

    float* outp = attn + (size_t)(b * 2 + g) * 18 * HW + hw;
#pragma unroll
    for (int half = 0; half < 2; ++half) {
        int base = half * 9;
        float m = e[base];
#pragma unroll
        for (int k = 1; k < 9; ++k) m = fmaxf(m, e[base + k]);
        float sum = 0.f, ex[9];
#pragma unroll
        for (int k = 0; k < 9; ++k) { ex[k] = expf(e[base + k] - m); sum += ex[k]; }
        float inv = 1.0f / sum;
#pragma unroll
        for (int k = 0; k < 9; ++k) outp[(size_t)(base + k) * HW] = ex[k] * inv;
    }
}

// ---------------------------------------------------------------------------
extern "C" void kernel_launch(void* const* d_in, const int* in_sizes, int n_in,
                              void* d_out, int out_size, void* d_ws, size_t ws_size,
                              hipStream_t stream) {
    const float* x      = (const float*)d_in[0];
    const float* pin_w  = (const float*)d_in[1];
    const float* ctx_w  = (const float*)d_in[2];
    const float* ctx1_w = (const float*)d_in[3];
    const float* ctx2_w = (const float*)d_in[4];
    const float* pout_w = (const float*)d_in[5];
    const float* cm0_q  = (const float*)d_in[6];
    const float* cm0_k  = (const float*)d_in[7];
    const float* cm0_p  = (const float*)d_in[8];
    const float* cm0_pb = (const float*)d_in[9];
    const float* cm0_o  = (const float*)d_in[10];
    const float* cm1_q  = (const float*)d_in[11];
    const float* cm1_k  = (const float*)d_in[12];
    const float* cm1_p  = (const float*)d_in[13];
    const float* cm1_pb = (const float*)d_in[14];
    const float* cm1_o  = (const float*)d_in[15];
    const float* cm2_q  = (const float*)d_in[16];
    const float* cm2_k  = (const float*)d_in[17];
    const float* cm2_p  = (const float*)d_in[18];
    const float* cm2_pb = (const float*)d_in[19];
    const float* cm2_o  = (const float*)d_in[20];
    float* out = (float*)d_out;

    float* ws = (float*)d_ws;
    // ---- fp32 region (floats, ends 35449568 = 141.8 MB) ----
    float* x_in  = ws;                          // [2,344,HW]
    float* x1p   = ws;                          // [2,172,HW] (after x_in dead)
    float* prod  = ws + 8630272;                // [2,172,HW]
    float* x_dw  = ws + 17260544;               // [2,344,HW]
    float* ctxb  = ws + 25890816;               // [2,86,HW]
    float* ctx1  = ws + 28048384;               // [2,43,HW]
    float* ctx2  = ws + 29127168;               // [2,43,HW]
    float* q0    = ws + 30205952;               // [2,172,HW]
    float* q1    = ws + 30205952;               // [2,86,HW]
    float* q2    = ws + 32363520;               // [2,86,HW]
    float* attnb = ws + 34521088;               // [2,2,18,HW]
    float* pooled= ws + 35424256;               // [2,86,49]
    float* keyb  = ws + 35432704;               // [2,172,49]
    // ---- bf16 region (ushorts; ends 40953856 sh = 81.9 MB; total ws 223.7 MB) ----
    unsigned short* ub = (unsigned short*)(ws + 35449568);
    // conv entries: 0 pin | 1 ctx+q0 | 2 cm0_o(restacked 172/192) | 3 ctx1+q1
    //               4 ctx2+q2 | 5 cm1_o | 6 cm2_o | 7 pout   (Mp mult of 32)
    static const int WOFF[8] = {0, 45056, 247808, 518144, 579584, 641024, 714752, 788480};
    static const int WO1[8]  = {344, 86, 172, 43, 43, 172, 172, 64};
    static const int WO2[8]  = {0, 172, 172, 86, 86, 0, 0, 0};
    static const int O2B[8]  = {352, 86, 192, 43, 43, 192, 192, 64};
    static const int WK[8]   = {64, 344, 344, 172, 172, 172, 172, 172};
    static const int WKP[8]  = {64, 352, 352, 192, 192, 192, 192, 192};
    static const int WMP[8]  = {352, 288, 384, 160, 160, 192, 192, 64};
    // X_t planes (weights end at 813056)
    unsigned short* xt_hi   = ub + 813056;      // [2][49][2][8192]
    unsigned short* xt_lo   = ub + 2418688;     // end 4024320
    // bigA slab [2][49][11][8192]; serially reused: xint -> y0t -> pt(KC=6)
    unsigned short* bigA_hi = ub + 4024320;
    unsigned short* bigA_lo = ub + 12855296;    // end 21686272
    unsigned short* x1t_hi  = ub + 21686272;    // [2][49][6][8192]; later y1t
    unsigned short* x1t_lo  = ub + 26503168;    // end 31320064
    unsigned short* x2t_hi  = ub + 31320064;    // later y2t
    unsigned short* x2t_lo  = ub + 36136960;    // end 40953856

    const float sc0 = 1.0f / sqrtf(86.0f);
    const float sc1 = 1.0f / sqrtf(43.0f);
    const size_t BS344 = (size_t)344 * HW, BS172 = (size_t)172 * HW,
                 BS86 = (size_t)86 * HW, BS64 = (size_t)64 * HW, BS43 = (size_t)43 * HW;

    // ---- 0. split/restack all weights (q-scales folded in, blocked layout) ----
    WSplitArgs wa;
    const float* wsrc1[8] = {pin_w, ctx_w, cm0_o, ctx1_w, ctx2_w, cm1_o, cm2_o, pout_w};
    const float* wsrc2[8] = {nullptr, cm0_q, cm0_o + (size_t)172 * 344, cm1_q, cm2_q,
                             nullptr, nullptr, nullptr};
    const float wsc2[8]   = {1.f, sc0, 1.f, sc1, sc1, 1.f, 1.f, 1.f};
    for (int i = 0; i < 8; ++i) {
        wa.src[i] = wsrc1[i]; wa.src2[i] = wsrc2[i];
        wa.hi[i]  = ub + WOFF[i];
        wa.lo[i]  = ub + WOFF[i] + WMP[i] * WKP[i];
        wa.O1[i] = WO1[i]; wa.O2[i] = WO2[i]; wa.O2B[i] = O2B[i];
        wa.K[i] = WK[i]; wa.Kp[i] = WKP[i];
        wa.MpKp[i] = WMP[i] * WKP[i];
        wa.scale2[i] = wsc2[i];
    }
    wsplit_k<<<dim3(528, 8), 256, 0, stream>>>(wa);

#define WHI(CI) (ub + WOFF[CI])
#define WLO(CI) (ub + WOFF[CI] + WMP[CI] * WKP[CI])
#define GRID(CI) dim3((WMP[CI] / 32) * 56, B_SZ)

    // ---- pin: x_in = pin_w @ x ----
    tsplit_k<<<dim3(392, 2, B_SZ), 256, 0, stream>>>(x, BS64, 64, 2, xt_hi, xt_lo);
    gemm_k<64><<<GRID(0), 256, 0, stream>>>(
        xt_hi, xt_lo, WHI(0), WLO(0), WMP[0] / 32,
        x_in, 344, BS344, nullptr, 0, 0, 352, 0, 344,
        nullptr, 0, nullptr, 0);
    tsplit_k<<<dim3(392, 11, B_SZ), 256, 0, stream>>>(x_in, BS344, 344, 11, bigA_hi, bigA_lo);

    // ---- contmix0: fused ctx_dw + q0 ----
    gemm_k<352><<<GRID(1), 256, 0, stream>>>(
        bigA_hi, bigA_lo, WHI(1), WLO(1), WMP[1] / 32,
        ctxb, 86, BS86, q0, 172, BS172, 86, 0, 258,
        nullptr, 0, nullptr, 0);
    pool_k<<<dim3(86, B_SZ), dim3(64), 0, stream>>>(ctxb, pooled, 86);
    keygemm_k<<<dim3(172, B_SZ), dim3(64), 0, stream>>>(pooled, cm0_k, keyb, 86, 172);
    attn_k<<<dim3(49, 2, B_SZ), dim3(256), 0, stream>>>(q0, keyb, cm0_p, cm0_pb, attnb, 86);
    // fused dyndw + bf16T: y0 never materialized; bigA (xint dead) <- y0t
    dyndw_bt_k<<<dim3(49, 44, B_SZ), 256, 0, stream>>>(
        x_in, attnb, bigA_hi, bigA_lo, 344, 172, 86, BS344, 11);
    // x_dw = cm0_o @ y  (restacked: rows 0..172 -> x1, 192..364 -> x2)
    gemm_k<352><<<GRID(2), 256, 0, stream>>>(
        bigA_hi, bigA_lo, WHI(2), WLO(2), WMP[2] / 32,
        x_dw, 172, BS344, x_dw + BS172, 172, BS344, 192, 0, 384,
        nullptr, 0, nullptr, 0);

    // ---- transpose halves of x_dw ----
    tsplit_k<<<dim3(392, 6, B_SZ), 256, 0, stream>>>(x_dw, BS344, 172, 6, x1t_hi, x1t_lo);
    tsplit_k<<<dim3(392, 6, B_SZ), 256, 0, stream>>>(x_dw + BS172, BS344, 172, 6, x2t_hi, x2t_lo);

    // ---- contmix1 on x1 ----
    gemm_k<192><<<GRID(3), 256, 0, stream>>>(
        x1t_hi, x1t_lo, WHI(3), WLO(3), WMP[3] / 32,
        ctx1, 43, BS43, q1, 86, BS86, 43, 0, 129,
        nullptr, 0, nullptr, 0);
    pool_k<<<dim3(43, B_SZ), dim3(64), 0, stream>>>(ctx1, pooled, 43);
    keygemm_k<<<dim3(86, B_SZ), dim3(64), 0, stream>>>(pooled, cm1_k, keyb, 43, 86);
    attn_k<<<dim3(49, 2, B_SZ), dim3(256), 0, stream>>>(q1, keyb, cm1_p, cm1_pb, attnb, 43);
    // fused dyndw + bf16T: x1t (dead after g3) <- y1t
    dyndw_bt_k<<<dim3(49, 24, B_SZ), 256, 0, stream>>>(
        x_dw, attnb, x1t_hi, x1t_lo, 172, 86, 43, BS344, 6);
    // x1p = tanh(cm1_o @ y1) + x1
    gemm_k<192><<<GRID(5), 256, 0, stream>>>(
        x1t_hi, x1t_lo, WHI(5), WLO(5), WMP[5] / 32,
        x1p, 172, BS172, nullptr, 0, 0, 192, 2, 172,
        x_dw, BS344, nullptr, 0);

    // ---- contmix2 on x2 ----
    gemm_k<192><<<GRID(4), 256, 0, stream>>>(
        x2t_hi, x2t_lo, WHI(4), WLO(4), WMP[4] / 32,
        ctx2, 43, BS43, q2, 86, BS86, 43, 0, 129,
        nullptr, 0, nullptr, 0);
    pool_k<<<dim3(43, B_SZ), dim3(64), 0, stream>>>(ctx2, pooled, 43);
    keygemm_k<<<dim3(86, B_SZ), dim3(64), 0, stream>>>(pooled, cm2_k, keyb, 43, 86);
    attn_k<<<dim3(49, 2, B_SZ), dim3(256), 0, stream>>>(q2, keyb, cm2_p, cm2_pb, attnb, 43);
    // fused dyndw + bf16T: x2t (dead after g4) <- y2t
    dyndw_bt_k<<<dim3(49, 24, B_SZ), 256, 0, stream>>>(
        x_dw + BS172, attnb, x2t_hi, x2t_lo, 172, 86, 43, BS344, 6);
    // prod = (tanh(cm2_o @ y2) + x2) * x1p
    gemm_k<192><<<GRID(6), 256, 0, stream>>>(
        x2t_hi, x2t_lo, WHI(6), WLO(6), WMP[6] / 32,
        prod, 172, BS172, nullptr, 0, 0, 192, 3, 172,
        x_dw + BS172, BS344, x1p, BS172);

    // ---- pout ----
    tsplit_k<<<dim3(392, 6, B_SZ), 256, 0, stream>>>(prod, BS172, 172, 6, bigA_hi, bigA_lo);
    gemm_k<192><<<GRID(7), 256, 0, stream>>>(
        bigA_hi, bigA_lo, WHI(7), WLO(7), WMP[7] / 32,
        out, 64, BS64, nullptr, 0, 0, 64, 0, 64,
        nullptr, 0, nullptr, 0);

#undef WHI
#undef WLO
#undef GRID
}

// Round 14
// 442.571 us; speedup vs baseline: 1.4890x; 1.2024x over previous
//
#include <hip/hip_runtime.h>
#include <math.h>

#define HW 12544      // 112*112
#define W_IMG 112
#define B_SZ 2

typedef __attribute__((ext_vector_type(8))) short s8v;   // 8 bf16 (4 VGPRs)
typedef __attribute__((ext_vector_type(4))) float f4v;   // MFMA acc

__device__ __forceinline__ void split_bf16(float x, unsigned short& h, unsigned short& l) {
    unsigned u  = __float_as_uint(x);
    unsigned hb = (u + 0x7FFFu + ((u >> 16) & 1u)) >> 16;
    float hf    = __uint_as_float(hb << 16);
    float r     = x - hf;
    unsigned ur = __float_as_uint(r);
    unsigned lb = (ur + 0x7FFFu + ((ur >> 16) & 1u)) >> 16;
    h = (unsigned short)hb; l = (unsigned short)lb;
}

// ---------------------------------------------------------------------------
// Weight split -> blocked transposed-quad bf16 hi/lo:
// [mblk(32 rows)][kc][kq(4)][32 rows][8 shorts].
// ---------------------------------------------------------------------------
struct WSplitArgs {
    const float* src[8];
    const float* src2[8];
    unsigned short* hi[8];
    unsigned short* lo[8];
    int O1[8]; int O2[8]; int O2B[8]; int K[8]; int Kp[8]; int MpKp[8];
    float scale2[8];
};

__global__ __launch_bounds__(256) void wsplit_k(WSplitArgs a) {
    const int ci  = blockIdx.y;
    const int idx = blockIdx.x * 256 + threadIdx.x;
    if (idx >= a.MpKp[ci]) return;
    const int Kp   = a.Kp[ci];
    const int blk  = 32 * Kp;
    const int mblk = idx / blk;
    const int rem  = idx - mblk * blk;
    const int kc   = rem >> 10;
    const int rem2 = rem & 1023;
    const int kq   = rem2 >> 8;
    const int row  = (rem2 >> 3) & 31;
    const int j    = rem2 & 7;
    const int o = mblk * 32 + row, k = kc * 32 + kq * 8 + j;
    float v = 0.f;
    if (k < a.K[ci]) {
        if (o < a.O1[ci])
            v = a.src[ci][(size_t)o * a.K[ci] + k];
        else if (o >= a.O2B[ci] && o - a.O2B[ci] < a.O2[ci])
            v = a.src2[ci][(size_t)(o - a.O2B[ci]) * a.K[ci] + k] * a.scale2[ci];
    }
    unsigned short h, l;
    split_bf16(v, h, l);
    a.hi[ci][idx] = h; a.lo[ci][idx] = l;
}

// ---------------------------------------------------------------------------
// Transpose + split: fp32 [C][HW] -> blocked transposed-quad bf16 hi/lo
// [b][strip(49)][kc][kq(4)][256 rows][8 shorts].  grid (392, KC, B).
// ---------------------------------------------------------------------------
__global__ __launch_bounds__(256) void tsplit_k(
    const float* __restrict__ src, size_t bstride, int C, int KC,
    unsigned short* __restrict__ hi, unsigned short* __restrict__ lo)
{
    __shared__ __align__(16) float t[32][36];
    const int b   = blockIdx.z;
    const int hw0 = blockIdx.x * 32;
    const int kc  = blockIdx.y;
    const int c0  = kc * 32;
    const int tid = threadIdx.x;

    {
        const int cl = tid >> 3, hq = (tid & 7) * 4;
        const int c  = c0 + cl;
        float4 v = make_float4(0.f, 0.f, 0.f, 0.f);
        if (c < C)
            v = *(const float4*)(src + (size_t)b * bstride + (size_t)c * HW + hw0 + hq);
        *(float4*)&t[cl][hq] = v;
    }
    __syncthreads();

    const int hl = tid >> 3, cq = (tid & 7) * 4;
    float v0 = t[cq + 0][hl], v1 = t[cq + 1][hl], v2 = t[cq + 2][hl], v3 = t[cq + 3][hl];
    ushort4 h4, l4;
    split_bf16(v0, h4.x, l4.x);
    split_bf16(v1, h4.y, l4.y);
    split_bf16(v2, h4.z, l4.z);
    split_bf16(v3, h4.w, l4.w);
    const int ns = hw0 >> 8, r = (hw0 & 255) + hl;
    const int kq = cq >> 3, j0 = cq & 7;
    const size_t base = (((size_t)b * 49 + ns) * KC + kc) * 8192
                        + (size_t)kq * 2048 + (size_t)r * 8 + j0;
    *(ushort4*)(hi + base) = h4;
    *(ushort4*)(lo + base) = l4;
}

// ---------------------------------------------------------------------------
// Batched (both halves of x_dw) transpose+split. grid (392, 6, 2*B).
// z: b = z&1, br = z>>1.  src ch = br*172 + c.
// ---------------------------------------------------------------------------
__global__ __launch_bounds__(256) void tsplit2_k(
    const float* __restrict__ src, size_t bstride,
    unsigned short* __restrict__ hi_a, unsigned short* __restrict__ lo_a,
    unsigned short* __restrict__ hi_b, unsigned short* __restrict__ lo_b)
{
    __shared__ __align__(16) float t[32][36];
    const int zz = blockIdx.z, b = zz & 1, br = zz >> 1;
    const int hw0 = blockIdx.x * 32;
    const int kc  = blockIdx.y;
    const int c0  = kc * 32;
    const int tid = threadIdx.x;

    {
        const int cl = tid >> 3, hq = (tid & 7) * 4;
        const int c  = c0 + cl;
        float4 v = make_float4(0.f, 0.f, 0.f, 0.f);
        if (c < 172)
            v = *(const float4*)(src + (size_t)b * bstride
                                 + (size_t)(br * 172 + c) * HW + hw0 + hq);
        *(float4*)&t[cl][hq] = v;
    }
    __syncthreads();

    const int hl = tid >> 3, cq = (tid & 7) * 4;
    float v0 = t[cq + 0][hl], v1 = t[cq + 1][hl], v2 = t[cq + 2][hl], v3 = t[cq + 3][hl];
    ushort4 h4, l4;
    split_bf16(v0, h4.x, l4.x);
    split_bf16(v1, h4.y, l4.y);
    split_bf16(v2, h4.z, l4.z);
    split_bf16(v3, h4.w, l4.w);
    const int ns = hw0 >> 8, r = (hw0 & 255) + hl;
    const int kq = cq >> 3, j0 = cq & 7;
    const size_t base = (((size_t)b * 49 + ns) * 6 + kc) * 8192
                        + (size_t)kq * 2048 + (size_t)r * 8 + j0;
    unsigned short* hi = br ? hi_b : hi_a;
    unsigned short* lo = br ? lo_b : lo_a;
    *(ushort4*)(hi + base) = h4;
    *(ushort4*)(lo + base) = l4;
}

// ---------------------------------------------------------------------------
// Fused elementwise multiply + transpose/split: p = t1*t2 -> blocked bf16T.
// grid (392, 6, B).
// ---------------------------------------------------------------------------
__global__ __launch_bounds__(256) void mulsplit_k(
    const float* __restrict__ t1, const float* __restrict__ t2, size_t bstride,
    unsigned short* __restrict__ hi, unsigned short* __restrict__ lo)
{
    __shared__ __align__(16) float t[32][36];
    const int b   = blockIdx.z;
    const int hw0 = blockIdx.x * 32;
    const int kc  = blockIdx.y;
    const int c0  = kc * 32;
    const int tid = threadIdx.x;

    {
        const int cl = tid >> 3, hq = (tid & 7) * 4;
        const int c  = c0 + cl;
        float4 v = make_float4(0.f, 0.f, 0.f, 0.f);
        if (c < 172) {
            const size_t off = (size_t)b * bstride + (size_t)c * HW + hw0 + hq;
            float4 a = *(const float4*)(t1 + off);
            float4 m = *(const float4*)(t2 + off);
            v = make_float4(a.x * m.x, a.y * m.y, a.z * m.z, a.w * m.w);
        }
        *(float4*)&t[cl][hq] = v;
    }
    __syncthreads();

    const int hl = tid >> 3, cq = (tid & 7) * 4;
    float v0 = t[cq + 0][hl], v1 = t[cq + 1][hl], v2 = t[cq + 2][hl], v3 = t[cq + 3][hl];
    ushort4 h4, l4;
    split_bf16(v0, h4.x, l4.x);
    split_bf16(v1, h4.y, l4.y);
    split_bf16(v2, h4.z, l4.z);
    split_bf16(v3, h4.w, l4.w);
    const int ns = hw0 >> 8, r = (hw0 & 255) + hl;
    const int kq = cq >> 3, j0 = cq & 7;
    const size_t base = (((size_t)b * 49 + ns) * 6 + kc) * 8192
                        + (size_t)kq * 2048 + (size_t)r * 8 + j0;
    *(ushort4*)(hi + base) = h4;
    *(ushort4*)(lo + base) = l4;
}

// ---------------------------------------------------------------------------
// Split-bf16 MFMA GEMM (single): LDS-staged conflict-free transposed-quad,
// register prefetch across barriers, XCD swizzle. mode 0 only.
// grid (per_m*56, B), block 256.
// ---------------------------------------------------------------------------
template <int KP>
__global__ __launch_bounds__(256) void gemm_k(
    const unsigned short* __restrict__ bt_hi, const unsigned short* __restrict__ bt_lo,
    const unsigned short* __restrict__ w_hi,  const unsigned short* __restrict__ w_lo,
    int per_m,
    float* __restrict__ outA, int OA, size_t oa_bstride,
    float* __restrict__ outB, int OB, size_t ob_bstride, int obase)
{
    constexpr int KC = KP / 32;
    __shared__ __align__(16) unsigned short Bh_s[8192];
    __shared__ __align__(16) unsigned short Bl_s[8192];
    __shared__ __align__(16) unsigned short Ah_s[1024];
    __shared__ __align__(16) unsigned short Al_s[1024];

    const int b   = blockIdx.y;
    const int bx  = blockIdx.x;
    const int xcd = bx & 7, t = bx >> 3;
    const int m   = t % per_m;
    const int ns  = (t / per_m) * 8 + xcd;
    if (ns >= 49) return;

    const int tid  = threadIdx.x;
    const int wv   = tid >> 6, lane = tid & 63;
    const int m16  = lane & 15, quad = lane >> 4;
    const int mbase = m * 32;
    const int nbase = ns * 256 + wv * 64;

    const unsigned short* Bh_g = bt_hi + ((size_t)b * 49 + ns) * KC * 8192;
    const unsigned short* Bl_g = bt_lo + ((size_t)b * 49 + ns) * KC * 8192;
    const unsigned short* Ah_g = w_hi + (size_t)m * KC * 1024;
    const unsigned short* Al_g = w_lo + (size_t)m * KC * 1024;

    f4v acc[2][4];
#pragma unroll
    for (int mt = 0; mt < 2; ++mt)
#pragma unroll
        for (int f = 0; f < 4; ++f) acc[mt][f] = (f4v){0.f, 0.f, 0.f, 0.f};

    s8v rB[8], rA;
#pragma unroll
    for (int j = 0; j < 4; ++j) {
        rB[j]     = *(const s8v*)(Bh_g + (size_t)(j * 256 + tid) * 8);
        rB[4 + j] = *(const s8v*)(Bl_g + (size_t)(j * 256 + tid) * 8);
    }
    rA = (tid < 128) ? *(const s8v*)(Ah_g + (size_t)tid * 8)
                     : *(const s8v*)(Al_g + (size_t)(tid - 128) * 8);
#pragma unroll
    for (int j = 0; j < 4; ++j) {
        *(s8v*)(Bh_s + (j * 256 + tid) * 8) = rB[j];
        *(s8v*)(Bl_s + (j * 256 + tid) * 8) = rB[4 + j];
    }
    if (tid < 128) *(s8v*)(Ah_s + tid * 8) = rA;
    else           *(s8v*)(Al_s + (tid - 128) * 8) = rA;
    __syncthreads();

#pragma unroll
    for (int kc = 0; kc < KC; ++kc) {
        if (kc + 1 < KC) {
            const unsigned short* bh = Bh_g + (size_t)(kc + 1) * 8192;
            const unsigned short* bl = Bl_g + (size_t)(kc + 1) * 8192;
#pragma unroll
            for (int j = 0; j < 4; ++j) {
                rB[j]     = *(const s8v*)(bh + (size_t)(j * 256 + tid) * 8);
                rB[4 + j] = *(const s8v*)(bl + (size_t)(j * 256 + tid) * 8);
            }
            rA = (tid < 128)
                ? *(const s8v*)(Ah_g + (size_t)(kc + 1) * 1024 + (size_t)tid * 8)
                : *(const s8v*)(Al_g + (size_t)(kc + 1) * 1024 + (size_t)(tid - 128) * 8);
        }
#pragma unroll
        for (int mt = 0; mt < 2; ++mt) {
            s8v ah = *(const s8v*)(Ah_s + (quad * 32 + mt * 16 + m16) * 8);
            s8v al = *(const s8v*)(Al_s + (quad * 32 + mt * 16 + m16) * 8);
#pragma unroll
            for (int f = 0; f < 4; ++f) {
                const int row = wv * 64 + f * 16 + m16;
                s8v bh = *(const s8v*)(Bh_s + (quad * 256 + row) * 8);
                s8v bl = *(const s8v*)(Bl_s + (quad * 256 + row) * 8);
                acc[mt][f] = __builtin_amdgcn_mfma_f32_16x16x32_bf16(ah, bh, acc[mt][f], 0, 0, 0);
                acc[mt][f] = __builtin_amdgcn_mfma_f32_16x16x32_bf16(al, bh, acc[mt][f], 0, 0, 0);
                acc[mt][f] = __builtin_amdgcn_mfma_f32_16x16x32_bf16(ah, bl, acc[mt][f], 0, 0, 0);
            }
        }
        __syncthreads();
        if (kc + 1 < KC) {
#pragma unroll
            for (int j = 0; j < 4; ++j) {
                *(s8v*)(Bh_s + (j * 256 + tid) * 8) = rB[j];
                *(s8v*)(Bl_s + (j * 256 + tid) * 8) = rB[4 + j];
            }
            if (tid < 128) *(s8v*)(Ah_s + tid * 8) = rA;
            else           *(s8v*)(Al_s + (tid - 128) * 8) = rA;
            __syncthreads();
        }
    }

#pragma unroll
    for (int mt = 0; mt < 2; ++mt) {
#pragma unroll
        for (int f = 0; f < 4; ++f) {
            const int n = nbase + f * 16 + m16;
#pragma unroll
            for (int r = 0; r < 4; ++r) {
                const int o = mbase + mt * 16 + quad * 4 + r;
                float v = acc[mt][f][r];
                if (o < OA) {
                    outA[(size_t)b * oa_bstride + (size_t)o * HW + n] = v;
                } else if (o >= obase && o - obase < OB) {
                    outB[(size_t)b * ob_bstride + (size_t)(o - obase) * HW + n] = v;
                }
            }
        }
    }
}

// ---------------------------------------------------------------------------
// Branch-batched GEMM: two independent (B,W,out,res) sets, selected by
// blockIdx.y>>1 (b = blockIdx.y&1). mode 0 or 2 (tanh+res for o<Ovalid).
// grid (per_m*56, 2*B), block 256.
// ---------------------------------------------------------------------------
template <int KP>
__global__ __launch_bounds__(256) void gemm2_k(
    const unsigned short* __restrict__ bth_a, const unsigned short* __restrict__ btl_a,
    const unsigned short* __restrict__ wh_a,  const unsigned short* __restrict__ wl_a,
    const unsigned short* __restrict__ bth_b, const unsigned short* __restrict__ btl_b,
    const unsigned short* __restrict__ wh_b,  const unsigned short* __restrict__ wl_b,
    int per_m,
    float* __restrict__ outA_a, float* __restrict__ outA_b, int OA, size_t oa_bstride,
    float* __restrict__ outB_a, float* __restrict__ outB_b, int OB, size_t ob_bstride, int obase,
    int mode, int Ovalid,
    const float* __restrict__ res_a, const float* __restrict__ res_b, size_t res_bstride)
{
    constexpr int KC = KP / 32;
    __shared__ __align__(16) unsigned short Bh_s[8192];
    __shared__ __align__(16) unsigned short Bl_s[8192];
    __shared__ __align__(16) unsigned short Ah_s[1024];
    __shared__ __align__(16) unsigned short Al_s[1024];

    const int zz  = blockIdx.y, b = zz & 1, br = zz >> 1;
    const int bx  = blockIdx.x;
    const int xcd = bx & 7, t = bx >> 3;
    const int m   = t % per_m;
    const int ns  = (t / per_m) * 8 + xcd;
    if (ns >= 49) return;

    const unsigned short* bt_hi = br ? bth_b : bth_a;
    const unsigned short* bt_lo = br ? btl_b : btl_a;
    const unsigned short* w_hi  = br ? wh_b : wh_a;
    const unsigned short* w_lo  = br ? wl_b : wl_a;
    float* outA = br ? outA_b : outA_a;
    float* outB = br ? outB_b : outB_a;
    const float* res = br ? res_b : res_a;

    const int tid  = threadIdx.x;
    const int wv   = tid >> 6, lane = tid & 63;
    const int m16  = lane & 15, quad = lane >> 4;
    const int mbase = m * 32;
    const int nbase = ns * 256 + wv * 64;

    const unsigned short* Bh_g = bt_hi + ((size_t)b * 49 + ns) * KC * 8192;
    const unsigned short* Bl_g = bt_lo + ((size_t)b * 49 + ns) * KC * 8192;
    const unsigned short* Ah_g = w_hi + (size_t)m * KC * 1024;
    const unsigned short* Al_g = w_lo + (size_t)m * KC * 1024;

    f4v acc[2][4];
#pragma unroll
    for (int mt = 0; mt < 2; ++mt)
#pragma unroll
        for (int f = 0; f < 4; ++f) acc[mt][f] = (f4v){0.f, 0.f, 0.f, 0.f};

    s8v rB[8], rA;
#pragma unroll
    for (int j = 0; j < 4; ++j) {
        rB[j]     = *(const s8v*)(Bh_g + (size_t)(j * 256 + tid) * 8);
        rB[4 + j] = *(const s8v*)(Bl_g + (size_t)(j * 256 + tid) * 8);
    }
    rA = (tid < 128) ? *(const s8v*)(Ah_g + (size_t)tid * 8)
                     : *(const s8v*)(Al_g + (size_t)(tid - 128) * 8);
#pragma unroll
    for (int j = 0; j < 4; ++j) {
        *(s8v*)(Bh_s + (j * 256 + tid) * 8) = rB[j];
        *(s8v*)(Bl_s + (j * 256 + tid) * 8) = rB[4 + j];
    }
    if (tid < 128) *(s8v*)(Ah_s + tid * 8) = rA;
    else           *(s8v*)(Al_s + (tid - 128) * 8) = rA;
    __syncthreads();

#pragma unroll
    for (int kc = 0; kc < KC; ++kc) {
        if (kc + 1 < KC) {
            const unsigned short* bh = Bh_g + (size_t)(kc + 1) * 8192;
            const unsigned short* bl = Bl_g + (size_t)(kc + 1) * 8192;
#pragma unroll
            for (int j = 0; j < 4; ++j) {
                rB[j]     = *(const s8v*)(bh + (size_t)(j * 256 + tid) * 8);
                rB[4 + j] = *(const s8v*)(bl + (size_t)(j * 256 + tid) * 8);
            }
            rA = (tid < 128)
                ? *(const s8v*)(Ah_g + (size_t)(kc + 1) * 1024 + (size_t)tid * 8)
                : *(const s8v*)(Al_g + (size_t)(kc + 1) * 1024 + (size_t)(tid - 128) * 8);
        }
#pragma unroll
        for (int mt = 0; mt < 2; ++mt) {
            s8v ah = *(const s8v*)(Ah_s + (quad * 32 + mt * 16 + m16) * 8);
            s8v al = *(const s8v*)(Al_s + (quad * 32 + mt * 16 + m16) * 8);
#pragma unroll
            for (int f = 0; f < 4; ++f) {
                const int row = wv * 64 + f * 16 + m16;
                s8v bh = *(const s8v*)(Bh_s + (quad * 256 + row) * 8);
                s8v bl = *(const s8v*)(Bl_s + (quad * 256 + row) * 8);
                acc[mt][f] = __builtin_amdgcn_mfma_f32_16x16x32_bf16(ah, bh, acc[mt][f], 0, 0, 0);
                acc[mt][f] = __builtin_amdgcn_mfma_f32_16x16x32_bf16(al, bh, acc[mt][f], 0, 0, 0);
                acc[mt][f] = __builtin_amdgcn_mfma_f32_16x16x32_bf16(ah, bl, acc[mt][f], 0, 0, 0);
            }
        }
        __syncthreads();
        if (kc + 1 < KC) {
#pragma unroll
            for (int j = 0; j < 4; ++j) {
                *(s8v*)(Bh_s + (j * 256 + tid) * 8) = rB[j];
                *(s8v*)(Bl_s + (j * 256 + tid) * 8) = rB[4 + j];
            }
            if (tid < 128) *(s8v*)(Ah_s + tid * 8) = rA;
            else           *(s8v*)(Al_s + (tid - 128) * 8) = rA;
            __syncthreads();
        }
    }

#pragma unroll
    for (int mt = 0; mt < 2; ++mt) {
#pragma unroll
        for (int f = 0; f < 4; ++f) {
            const int n = nbase + f * 16 + m16;
#pragma unroll
            for (int r = 0; r < 4; ++r) {
                const int o = mbase + mt * 16 + quad * 4 + r;
                float v = acc[mt][f][r];
                if (mode == 2 && o < Ovalid)
                    v = tanhf(v) + res[(size_t)b * res_bstride + (size_t)o * HW + n];
                if (o < OA) {
                    outA[(size_t)b * oa_bstride + (size_t)o * HW + n] = v;
                } else if (o >= obase && o - obase < OB) {
                    outB[(size_t)b * ob_bstride + (size_t)(o - obase) * HW + n] = v;
                }
            }
        }
    }
}

// ---------------------------------------------------------------------------
// FUSED dynamic depthwise 3x3 + bf16-split + blocked-transpose (contmix0).
// grid (49, Kp/8, B), block 256.
// ---------------------------------------------------------------------------
__global__ __launch_bounds__(256) void dyndw_bt_k(
    const float* __restrict__ x, const float* __restrict__ attn,
    unsigned short* __restrict__ hi, unsigned short* __restrict__ lo,
    int C, int C_half, int hd, size_t x_bstride, int KC)
{
    const int b  = blockIdx.z, ns = blockIdx.x, tid = threadIdx.x;
    const int c0 = blockIdx.y * 8;
    const int hw = ns * 256 + tid;
    const int h = hw / W_IMG, w = hw - h * W_IMG;

    int off[9]; bool val[9];
#pragma unroll
    for (int i = 0; i < 3; ++i)
#pragma unroll
        for (int j = 0; j < 3; ++j) {
            const int hh = h + i - 1, ww = w + j - 1;
            val[i * 3 + j] = (hh >= 0 && hh < 112 && ww >= 0 && ww < 112);
            off[i * 3 + j] = hh * W_IMG + ww;
        }

    s8v hvv, lvv;
#pragma unroll
    for (int u = 0; u < 8; ++u) {
        const int c = c0 + u;
        float acc = 0.f;
        if (c < C) {
            const int half = c / C_half;
            const int g = (c - half * C_half) / hd;
            const float* ap = attn + ((size_t)(b * 2 + g) * 18 + half * 9) * HW + hw;
            const float* xp = x + (size_t)b * x_bstride + (size_t)c * HW;
#pragma unroll
            for (int k = 0; k < 9; ++k) {
                const float xv = val[k] ? xp[off[k]] : 0.f;
                acc += ap[(size_t)k * HW] * xv;
            }
        }
        unsigned short hs, ls;
        split_bf16(acc, hs, ls);
        hvv[u] = (short)hs; lvv[u] = (short)ls;
    }

    const int kc = c0 >> 5, kq = (c0 & 31) >> 3;
    const size_t base = (((size_t)b * 49 + ns) * KC + kc) * 8192
                        + (size_t)kq * 2048 + (size_t)tid * 8;
    *(s8v*)(hi + base) = hvv;
    *(s8v*)(lo + base) = lvv;
}

// ---------------------------------------------------------------------------
// Branch-batched dyndw_bt for contmix1/2.  grid (49, 24, 2*B).
// z: b = z&1, br = z>>1.  C=172, C_half=86, hd=43, KC=6.
// ---------------------------------------------------------------------------
__global__ __launch_bounds__(256) void dyndw2_bt_k(
    const float* __restrict__ x, size_t x_bstride,
    const float* __restrict__ attn_a, const float* __restrict__ attn_b,
    unsigned short* __restrict__ hi_a, unsigned short* __restrict__ lo_a,
    unsigned short* __restrict__ hi_b, unsigned short* __restrict__ lo_b)
{
    const int zz = blockIdx.z, b = zz & 1, br = zz >> 1;
    const int ns = blockIdx.x, tid = threadIdx.x;
    const int c0 = blockIdx.y * 8;
    const int hw = ns * 256 + tid;
    const int h = hw / W_IMG, w = hw - h * W_IMG;

    const float* attn = br ? attn_b : attn_a;
    unsigned short* hi = br ? hi_b : hi_a;
    unsigned short* lo = br ? lo_b : lo_a;

    int off[9]; bool val[9];
#pragma unroll
    for (int i = 0; i < 3; ++i)
#pragma unroll
        for (int j = 0; j < 3; ++j) {
            const int hh = h + i - 1, ww = w + j - 1;
            val[i * 3 + j] = (hh >= 0 && hh < 112 && ww >= 0 && ww < 112);
            off[i * 3 + j] = hh * W_IMG + ww;
        }

    s8v hvv, lvv;
#pragma unroll
    for (int u = 0; u < 8; ++u) {
        const int c = c0 + u;
        float acc = 0.f;
        if (c < 172) {
            const int half = c / 86;
            const int g = (c - half * 86) / 43;
            const float* ap = attn + ((size_t)(b * 2 + g) * 18 + half * 9) * HW + hw;
            const float* xp = x + (size_t)b * x_bstride + (size_t)(br * 172 + c) * HW;
#pragma unroll
            for (int k = 0; k < 9; ++k) {
                const float xv = val[k] ? xp[off[k]] : 0.f;
                acc += ap[(size_t)k * HW] * xv;
            }
        }
        unsigned short hs, ls;
        split_bf16(acc, hs, ls);
        hvv[u] = (short)hs; lvv[u] = (short)ls;
    }

    const int kc = c0 >> 5, kq = (c0 & 31) >> 3;
    const size_t base = (((size_t)b * 49 + ns) * 6 + kc) * 8192
                        + (size_t)kq * 2048 + (size_t)tid * 8;
    *(s8v*)(hi + base) = hvv;
    *(s8v*)(lo + base) = lvv;
}

// ---------------------------------------------------------------------------
// 16x16 block mean-pool.  grid (C, B) / batched grid (C, 2*B).
// ---------------------------------------------------------------------------
__global__ __launch_bounds__(64) void pool_k(
    const float* __restrict__ ctx, float* __restrict__ pooled, int C)
{
    const int c = blockIdx.x, b = blockIdx.y, t = threadIdx.x;
    if (t >= 49) return;
    const int ph = t / 7, pw = t % 7;
    const float* src = ctx + ((size_t)b * C + c) * HW;
    float sum = 0.f;
    for (int i = 0; i < 16; ++i) {
        const float* row = src + (ph * 16 + i) * W_IMG + pw * 16;
        for (int j = 0; j < 16; ++j) sum += row[j];
    }
    pooled[((size_t)b * C + c) * 49 + t] = sum * (1.0f / 256.0f);
}

__global__ __launch_bounds__(64) void pool2_k(
    const float* __restrict__ ctx_a, const float* __restrict__ ctx_b,
    float* __restrict__ p_a, float* __restrict__ p_b, int C)
{
    const int zz = blockIdx.y, b = zz & 1, br = zz >> 1;
    const int c = blockIdx.x, t = threadIdx.x;
    if (t >= 49) return;
    const float* ctx = br ? ctx_b : ctx_a;
    float* pooled    = br ? p_b : p_a;
    const int ph = t / 7, pw = t % 7;
    const float* src = ctx + ((size_t)b * C + c) * HW;
    float sum = 0.f;
    for (int i = 0; i < 16; ++i) {
        const float* row = src + (ph * 16 + i) * W_IMG + pw * 16;
        for (int j = 0; j < 16; ++j) sum += row[j];
    }
    pooled[((size_t)b * C + c) * 49 + t] = sum * (1.0f / 256.0f);
}

// ---------------------------------------------------------------------------
// key = wk @ pooled.  single + batched.
// ---------------------------------------------------------------------------
__global__ __launch_bounds__(64) void keygemm_k(
    const float* __restrict__ pooled, const float* __restrict__ wk,
    float* __restrict__ key, int K, int O)
{
    const int o = blockIdx.x, b = blockIdx.y, l = threadIdx.x;
    if (l >= 49) return;
    float s = 0.f;
    for (int c = 0; c < K; ++c)
        s += wk[(size_t)o * K + c] * pooled[((size_t)b * K + c) * 49 + l];
    key[((size_t)b * O + o) * 49 + l] = s;
}

__global__ __launch_bounds__(64) void keygemm2_k(
    const float* __restrict__ p_a, const float* __restrict__ p_b,
    const float* __restrict__ wk_a, const float* __restrict__ wk_b,
    float* __restrict__ k_a, float* __restrict__ k_b, int K, int O)
{
    const int zz = blockIdx.y, b = zz & 1, br = zz >> 1;
    const int o = blockIdx.x, l = threadIdx.x;
    if (l >= 49) return;
    const float* pooled = br ? p_b : p_a;
    const float* wk     = br ? wk_b : wk_a;
    float* key          = br ? k_b : k_a;
    float s = 0.f;
    for (int c = 0; c < K; ++c)
        s += wk[(size_t)o * K + c] * pooled[((size_t)b * K + c) * 49 + l];
    key[((size_t)b * O + o) * 49 + l] = s;
}

// ---------------------------------------------------------------------------
// Attention scores + double softmax.  attn layout [b][g][18][HW].
// single: grid (49, 2, B).  batched: grid (49, 2, 2*B).
// ---------------------------------------------------------------------------
__device__ __forceinline__ void attn_body(
    const float* __restrict__ q, const float* __restrict__ key,
    const float* __restrict__ wp, const float* __restrict__ pb,
    float* __restrict__ attn, int hd, int b, int g, int tid, int nsx)
{
    __shared__ float klds[86 * 52];
    __shared__ float plds[18 * 52];
    __shared__ float pblds[18];

    for (int idx = tid; idx < hd * 49; idx += 256) {
        int c = idx / 49, l = idx - c * 49;
        klds[c * 52 + l] = key[((size_t)(b * 2 + g) * hd + c) * 49 + l];
    }
    for (int idx = tid; idx < hd * 3; idx += 256) {
        int c = idx / 3;
        klds[c * 52 + 49 + (idx - c * 3)] = 0.f;
    }
    for (int idx = tid; idx < 18 * 49; idx += 256) {
        int o = idx / 49, l = idx - o * 49;
        plds[o * 52 + l] = wp[o * 49 + l];
    }
    for (int idx = tid; idx < 18 * 3; idx += 256) {
        int o = idx / 3;
        plds[o * 52 + 49 + (idx - o * 3)] = 0.f;
    }
    if (tid < 18) pblds[tid] = pb[tid];
    __syncthreads();

    const int hw = nsx * 256 + tid;

    float4 s[13];
#pragma unroll
    for (int t = 0; t < 13; ++t) s[t] = make_float4(0.f, 0.f, 0.f, 0.f);

    const float* qp = q + (size_t)(b * 2 + g) * hd * HW + hw;
    for (int c = 0; c < hd; ++c) {
        float qv = qp[(size_t)c * HW];
        const float4* kr = (const float4*)(klds + c * 52);
#pragma unroll
        for (int t = 0; t < 13; ++t) {
            float4 kv = kr[t];
            s[t].x += qv * kv.x; s[t].y += qv * kv.y;
            s[t].z += qv * kv.z; s[t].w += qv * kv.w;
        }
    }

    float e[18];
#pragma unroll
    for (int o = 0; o < 18; ++o) {
        const float4* pr = (const float4*)(plds + o * 52);
        float4 a = make_float4(0.f, 0.f, 0.f, 0.f);
#pragma unroll
        for (int t = 0; t < 13; ++t) {
            float4 pv = pr[t];
            a.x += s[t].x * pv.x; a.y += s[t].y * pv.y;
            a.z += s[t].z * pv.z; a.w += s[t].w * pv.w;
        }
        e[o] = pblds[o] + a.x + a.y + a.z + a.w;
    }

    float* outp = attn + (size_t)(b * 2 + g) * 18 * HW + hw;
#pragma unroll
    for (int half = 0; half < 2; ++half) {
        int base = half * 9;
        float m = e[base];
#pragma unroll
        for (int k = 1; k < 9; ++k) m = fmaxf(m, e[base + k]);
        float sum = 0.f, ex[9];
#pragma unroll
        for (int k = 0; k < 9; ++k) { ex[k] = expf(e[base + k] - m); sum += ex[k]; }
        float inv = 1.0f / sum;
#pragma unroll
        for (int k = 0; k < 9; ++k) outp[(size_t)(base + k) * HW] = ex[k] * inv;
    }
}

__global__ __launch_bounds__(256) void attn_k(
    const float* __restrict__ q, const float* __restrict__ key,
    const float* __restrict__ wp, const float* __restrict__ pb,
    float* __restrict__ attn, int hd)
{
    attn_body(q, key, wp, pb, attn, hd, blockIdx.z, blockIdx.y, threadIdx.x, blockIdx.x);
}

__global__ __launch_bounds__(256) void attn2_k(
    const float* __restrict__ q_a, const float* __restrict__ q_b,
    const float* __restrict__ k_a, const float* __restrict__ k_b,
    const float* __restrict__ wp_a, const float* __restrict__ wp_b,
    const float* __restrict__ pb_a, const float* __restrict__ pb_b,
    float* __restrict__ at_a, float* __restrict__ at_b, int hd)
{
    const int zz = blockIdx.z, b = zz & 1, br = zz >> 1;
    attn_body(br ? q_b : q_a, br ? k_b : k_a, br ? wp_b : wp_a,
              br ? pb_b : pb_a, br ? at_b : at_a, hd, b, blockIdx.y,
              threadIdx.x, blockIdx.x);
}

// ---------------------------------------------------------------------------
extern "C" void kernel_launch(void* const* d_in, const int* in_sizes, int n_in,
                              void* d_out, int out_size, void* d_ws, size_t ws_size,
                              hipStream_t stream) {
    const float* x      = (const float*)d_in[0];
    const float* pin_w  = (const float*)d_in[1];
    const float* ctx_w  = (const float*)d_in[2];
    const float* ctx1_w = (const float*)d_in[3];
    const float* ctx2_w = (const float*)d_in[4];
    const float* pout_w = (const float*)d_in[5];
    const float* cm0_q  = (const float*)d_in[6];
    const float* cm0_k  = (const float*)d_in[7];
    const float* cm0_p  = (const float*)d_in[8];
    const float* cm0_pb = (const float*)d_in[9];
    const float* cm0_o  = (const float*)d_in[10];
    const float* cm1_q  = (const float*)d_in[11];
    const float* cm1_k  = (const float*)d_in[12];
    const float* cm1_p  = (const float*)d_in[13];
    const float* cm1_pb = (const float*)d_in[14];
    const float* cm1_o  = (const float*)d_in[15];
    const float* cm2_q  = (const float*)d_in[16];
    const float* cm2_k  = (const float*)d_in[17];
    const float* cm2_p  = (const float*)d_in[18];
    const float* cm2_pb = (const float*)d_in[19];
    const float* cm2_o  = (const float*)d_in[20];
    float* out = (float*)d_out;

    float* ws = (float*)d_ws;
    // ---- fp32 region (floats) ----
    float* x_in  = ws;                          // [2,344,HW]; later t1
    float* t1    = ws;                          // [2,172,HW]
    float* t2    = ws + 8630272;                // [2,172,HW]
    float* x_dw  = ws + 17260544;               // [2,344,HW]
    float* ctxb  = ws + 25890816;               // [2,86,HW]
    float* ctx1  = ws + 28048384;               // [2,43,HW]
    float* ctx2  = ws + 29127168;               // [2,43,HW]
    float* q0    = ws + 30205952;               // [2,172,HW]
    float* q1    = ws + 30205952;               // [2,86,HW]
    float* q2    = ws + 32363520;               // [2,86,HW]
    float* attn0 = ws + 34521088;               // [2,2,18,HW] = 903168
    float* attn1 = ws + 35424256;
    float* attn2 = ws + 36327424;
    float* pool0 = ws + 37230592;               // [2,86,49] = 8428
    float* pool1 = ws + 37239020;               // [2,43,49] = 4214
    float* pool2b= ws + 37243234;
    float* key0  = ws + 37247448;               // [2,172,49] = 16856
    float* key1  = ws + 37264304;               // [2,86,49]  = 8428
    float* key2  = ws + 37272732;               // ends 37281160 (149.1 MB)
    // ---- bf16 region (ushorts; 81.9 MB; total ws 231.0 MB < proven 246) ----
    unsigned short* ub = (unsigned short*)(ws + 37281160);
    static const int WOFF[8] = {0, 45056, 247808, 518144, 579584, 641024, 714752, 788480};
    static const int WO1[8]  = {344, 86, 172, 43, 43, 172, 172, 64};
    static const int WO2[8]  = {0, 172, 172, 86, 86, 0, 0, 0};
    static const int O2B[8]  = {352, 86, 192, 43, 43, 192, 192, 64};
    static const int WK[8]   = {64, 344, 344, 172, 172, 172, 172, 172};
    static const int WKP[8]  = {64, 352, 352, 192, 192, 192, 192, 192};
    static const int WMP[8]  = {352, 288, 384, 160, 160, 192, 192, 64};
    unsigned short* xt_hi   = ub + 813056;      // [2][49][2][8192]
    unsigned short* xt_lo   = ub + 2418688;     // end 4024320
    unsigned short* bigA_hi = ub + 4024320;     // [2][49][11][8192]: xint -> y0t -> pt
    unsigned short* bigA_lo = ub + 12855296;    // end 21686272
    unsigned short* x1t_hi  = ub + 21686272;    // [2][49][6][8192]; later y1t
    unsigned short* x1t_lo  = ub + 26503168;
    unsigned short* x2t_hi  = ub + 31320064;    // later y2t
    unsigned short* x2t_lo  = ub + 36136960;    // end 40953856

    const float sc0 = 1.0f / sqrtf(86.0f);
    const float sc1 = 1.0f / sqrtf(43.0f);
    const size_t BS344 = (size_t)344 * HW, BS172 = (size_t)172 * HW,
                 BS86 = (size_t)86 * HW, BS64 = (size_t)64 * HW, BS43 = (size_t)43 * HW;

    // ---- 0. weight split (q-scales folded, blocked layout) ----
    WSplitArgs wa;
    const float* wsrc1[8] = {pin_w, ctx_w, cm0_o, ctx1_w, ctx2_w, cm1_o, cm2_o, pout_w};
    const float* wsrc2[8] = {nullptr, cm0_q, cm0_o + (size_t)172 * 344, cm1_q, cm2_q,
                             nullptr, nullptr, nullptr};
    const float wsc2[8]   = {1.f, sc0, 1.f, sc1, sc1, 1.f, 1.f, 1.f};
    for (int i = 0; i < 8; ++i) {
        wa.src[i] = wsrc1[i]; wa.src2[i] = wsrc2[i];
        wa.hi[i]  = ub + WOFF[i];
        wa.lo[i]  = ub + WOFF[i] + WMP[i] * WKP[i];
        wa.O1[i] = WO1[i]; wa.O2[i] = WO2[i]; wa.O2B[i] = O2B[i];
        wa.K[i] = WK[i]; wa.Kp[i] = WKP[i];
        wa.MpKp[i] = WMP[i] * WKP[i];
        wa.scale2[i] = wsc2[i];
    }
    wsplit_k<<<dim3(528, 8), 256, 0, stream>>>(wa);

#define WHI(CI) (ub + WOFF[CI])
#define WLO(CI) (ub + WOFF[CI] + WMP[CI] * WKP[CI])
#define GRID(CI) dim3((WMP[CI] / 32) * 56, B_SZ)
#define GRID2(CI) dim3((WMP[CI] / 32) * 56, 2 * B_SZ)

    // ---- pin ----
    tsplit_k<<<dim3(392, 2, B_SZ), 256, 0, stream>>>(x, BS64, 64, 2, xt_hi, xt_lo);
    gemm_k<64><<<GRID(0), 256, 0, stream>>>(
        xt_hi, xt_lo, WHI(0), WLO(0), WMP[0] / 32,
        x_in, 344, BS344, nullptr, 0, 0, 352);
    tsplit_k<<<dim3(392, 11, B_SZ), 256, 0, stream>>>(x_in, BS344, 344, 11, bigA_hi, bigA_lo);

    // ---- contmix0 ----
    gemm_k<352><<<GRID(1), 256, 0, stream>>>(
        bigA_hi, bigA_lo, WHI(1), WLO(1), WMP[1] / 32,
        ctxb, 86, BS86, q0, 172, BS172, 86);
    pool_k<<<dim3(86, B_SZ), dim3(64), 0, stream>>>(ctxb, pool0, 86);
    keygemm_k<<<dim3(172, B_SZ), dim3(64), 0, stream>>>(pool0, cm0_k, key0, 86, 172);
    attn_k<<<dim3(49, 2, B_SZ), dim3(256), 0, stream>>>(q0, key0, cm0_p, cm0_pb, attn0, 86);
    dyndw_bt_k<<<dim3(49, 44, B_SZ), 256, 0, stream>>>(
        x_in, attn0, bigA_hi, bigA_lo, 344, 172, 86, BS344, 11);
    gemm_k<352><<<GRID(2), 256, 0, stream>>>(
        bigA_hi, bigA_lo, WHI(2), WLO(2), WMP[2] / 32,
        x_dw, 172, BS344, x_dw + BS172, 172, BS344, 192);

    // ---- batched x1/x2 transpose ----
    tsplit2_k<<<dim3(392, 6, 2 * B_SZ), 256, 0, stream>>>(
        x_dw, BS344, x1t_hi, x1t_lo, x2t_hi, x2t_lo);

    // ---- branch-batched contmix1+contmix2 ----
    gemm2_k<192><<<GRID2(3), 256, 0, stream>>>(
        x1t_hi, x1t_lo, WHI(3), WLO(3),
        x2t_hi, x2t_lo, WHI(4), WLO(4), WMP[3] / 32,
        ctx1, ctx2, 43, BS43,
        q1, q2, 86, BS86, 43,
        0, 129, nullptr, nullptr, 0);
    pool2_k<<<dim3(43, 2 * B_SZ), dim3(64), 0, stream>>>(ctx1, ctx2, pool1, pool2b, 43);
    keygemm2_k<<<dim3(86, 2 * B_SZ), dim3(64), 0, stream>>>(
        pool1, pool2b, cm1_k, cm2_k, key1, key2, 43, 86);
    attn2_k<<<dim3(49, 2, 2 * B_SZ), dim3(256), 0, stream>>>(
        q1, q2, key1, key2, cm1_p, cm2_p, cm1_pb, cm2_pb, attn1, attn2, 43);
    dyndw2_bt_k<<<dim3(49, 24, 2 * B_SZ), 256, 0, stream>>>(
        x_dw, BS344, attn1, attn2, x1t_hi, x1t_lo, x2t_hi, x2t_lo);
    // t1 = tanh(cm1_o@y1)+x1 ; t2 = tanh(cm2_o@y2)+x2   (batched, mode 2)
    gemm2_k<192><<<GRID2(5), 256, 0, stream>>>(
        x1t_hi, x1t_lo, WHI(5), WLO(5),
        x2t_hi, x2t_lo, WHI(6), WLO(6), WMP[5] / 32,
        t1, t2, 172, BS172,
        nullptr, nullptr, 0, 0, 192,
        2, 172, x_dw, x_dw + BS172, BS344);

    // ---- prod = t1*t2 -> blocked bf16T (fused) ----
    mulsplit_k<<<dim3(392, 6, B_SZ), 256, 0, stream>>>(t1, t2, BS172, bigA_hi, bigA_lo);

    // ---- pout ----
    gemm_k<192><<<GRID(7), 256, 0, stream>>>(
        bigA_hi, bigA_lo, WHI(7), WLO(7), WMP[7] / 32,
        out, 64, BS64, nullptr, 0, 0, 64);

#undef WHI
#undef WLO
#undef GRID
#undef GRID2
}